// Round 7
// baseline (638.348 us; speedup 1.0000x reference)
//
#include <hip/hip_runtime.h>
#include <hip/hip_fp16.h>
#include <math.h>

typedef unsigned short u16;
typedef unsigned int u32;
typedef _Float16 half2_t __attribute__((ext_vector_type(2)));
typedef _Float16 f16x8 __attribute__((ext_vector_type(8)));
typedef float f32x4 __attribute__((ext_vector_type(4)));

#define B0N 8
#define LSEQ 9216
#define NSEQ 64
#define NCHUNK 288
#define DM 32
#define DPROJ 264
#define CONVCH 192
#define XC4 208   // k4 xc row stride (fp16, 416B rows -> 16B-aligned for ds_read_b128)
#define URH 40    // ur row stride (fp16, 80B rows -> 16B-aligned, 2-way banks)
#define CHH 204   // k4 CH row stride (fp16)
#define ZBS 66    // k4 zbuf row stride (fp16)
#define C2H 132   // k2 CH row stride (fp16, 264B rows; conv reads are scalar)
#define TTS 40    // k2 transposed xs/B/A row stride (fp16, 80B rows)
#define GS 36     // k4 G row stride (f32, 144B rows -> 16B-aligned)
#define YH5 264   // k5 yh row stride (fp16, 528B rows -> 16B-aligned)

#ifndef __has_builtin
#define __has_builtin(x) 0
#endif

__device__ __forceinline__ float silu_(float v) { return v / (1.f + __expf(-v)); }

// ---------------- K1: LayerNorm(256) + split -> u (64,9216,32) fp16 ----------------
__global__ __launch_bounds__(256) void k1_ln_split(const float* __restrict__ x,
                                                   const float* __restrict__ lnw,
                                                   const float* __restrict__ lnb,
                                                   __half* __restrict__ u) {
  __shared__ float tile[256 * 33];  // [c][ll]
  __shared__ float mu[32], rs[32], wv[256], bv[256];
  __shared__ float ps[32 * 9], ps2[32 * 9];
  const int b = blockIdx.y, l0 = blockIdx.x * 32, t = threadIdx.x;
  wv[t] = lnw[t];
  bv[t] = lnb[t];
#pragma unroll 4
  for (int i = 0; i < 32; ++i) {
    int c = i * 8 + (t >> 5), ll = t & 31;
    tile[c * 33 + ll] = x[((size_t)b * 256 + c) * LSEQ + l0 + ll];
  }
  __syncthreads();
  {
    const int ll = t & 31, seg = t >> 5;
    float s = 0.f, s2 = 0.f;
#pragma unroll 8
    for (int i = 0; i < 32; ++i) {
      float v = tile[(seg * 32 + i) * 33 + ll];
      s += v; s2 += v * v;
    }
    ps[ll * 9 + seg] = s;
    ps2[ll * 9 + seg] = s2;
  }
  __syncthreads();
  if (t < 32) {
    float s = 0.f, s2 = 0.f;
#pragma unroll
    for (int seg = 0; seg < 8; ++seg) { s += ps[t * 9 + seg]; s2 += ps2[t * 9 + seg]; }
    float m = s * (1.f / 256.f);
    mu[t] = m;
    rs[t] = rsqrtf(s2 * (1.f / 256.f) - m * m + 1e-5f);
  }
  __syncthreads();
#pragma unroll 4
  for (int i = 0; i < 32; ++i) {
    int sp = i >> 2, sub = i & 3;
    int ll = sub * 8 + (t >> 5), dm = t & 31;
    int c = sp * 32 + dm;
    float v = (tile[c * 33 + ll] - mu[ll]) * rs[ll] * wv[c] + bv[c];
    u[(((size_t)(sp * B0N + b)) * LSEQ + l0 + ll) * DM + dm] = __float2half(v);
  }
}

// ---------------- K2: in-proj + conv + dt + per-chunk states (MFMA, fp16 CH) ----------------
// LDS arena (32512 B -> 5 blocks/CU):
//   ur_h  [48][URH] fp16 @ 0      (3840 B)
//   CH2h  [34][C2H] fp16 @ 3840   (8976 B)   dead after conv
//   Ah    [64][TTS] fp16 @ 3840   (5120 B)   overlay (inside CH2h region)
//   Sout  [64][72]  fp16 @ 8960   (9216 B)   overlay (CH2h tail; disjoint from Ah)
//   xst   [64][TTS] fp16 @ 18176  (5120 B)
//   Bt    [64][TTS] fp16 @ 23296  (5120 B)
//   dtraw/dtv/acs/wv2 f32[256] @ 28416..32512
__global__ __launch_bounds__(256, 5) void k2_states(
    const __half* __restrict__ u, const float* __restrict__ Win,
    const float* __restrict__ convw, const float* __restrict__ convb,
    const float* __restrict__ dtbias, const float* __restrict__ Alog,
    __half* __restrict__ S, float* __restrict__ cdec) {
  __shared__ __align__(16) char smem[32512];
  _Float16* ur_h = (_Float16*)smem;
  _Float16* CH2h = (_Float16*)(smem + 3840);
  _Float16* Ah   = (_Float16*)(smem + 3840);
  __half*   Sout = (__half*)(smem + 8960);
  _Float16* xst  = (_Float16*)(smem + 18176);
  _Float16* Bt   = (_Float16*)(smem + 23296);
  float* dtraw = (float*)(smem + 28416);
  float* dtv   = (float*)(smem + 29440);
  float* acs   = (float*)(smem + 30464);
  float* wv2   = (float*)(smem + 31488);
  const int c = blockIdx.x, sq = blockIdx.y, t = threadIdx.x;
  const int l0 = c * 32;
  const int lane = t & 63, wvi = t >> 6, g = lane >> 4, c16 = lane & 15;
  const size_t ubase = (size_t)sq * (LSEQ * DM);
  const f32x4 zero4 = {0.f, 0.f, 0.f, 0.f};

  // ---- P0: stage ur (fp16); load Win B-frags (cols 64..191 -> channels 0..127) ----
  for (int idx = t; idx < 48 * 32; idx += 256) {
    int r = idx >> 5, dm = idx & 31;
    int l = l0 - 2 + r;
    _Float16 v = (_Float16)0.f;
    if (r < 34 && l >= 0) v = ((const _Float16*)u)[ubase + (size_t)l * DM + dm];
    ur_h[r * URH + dm] = v;
  }
  f16x8 bfr[2];  // N-tiles nt = wvi, wvi+4
#pragma unroll
  for (int i = 0; i < 2; ++i) {
    int col = 64 + (wvi + i * 4) * 16 + c16;
#pragma unroll
    for (int j = 0; j < 8; ++j) bfr[i][j] = (_Float16)Win[(g * 8 + j) * DPROJ + col];
  }
  __syncthreads();

  // ---- P1: MFMA inproj -> CH2h (34 rows x 128 channels, fp16) ----
  {
    f16x8 am[3];
#pragma unroll
    for (int mt = 0; mt < 3; ++mt)
      am[mt] = *(const f16x8*)&ur_h[(mt * 16 + c16) * URH + g * 8];
#pragma unroll
    for (int i = 0; i < 2; ++i) {
      int colc = (wvi + i * 4) * 16 + c16;
#pragma unroll
      for (int mt = 0; mt < 3; ++mt) {
        f32x4 acc = __builtin_amdgcn_mfma_f32_16x16x32_f16(am[mt], bfr[i], zero4, 0, 0, 0);
#pragma unroll
        for (int r = 0; r < 4; ++r) {
          int R = mt * 16 + 4 * g + r;
          if (R < 34) CH2h[R * C2H + colc] = (_Float16)acc[r];
        }
      }
    }
  }
  __syncthreads();

  // ---- P2: conv+silu -> xst/Bt (rolling 3-tap, f16x8 row stores); dtraw f32 dot ----
  {
    const int ch0 = t & 63, lbq = t >> 6;  // rows lbq*8 .. lbq*8+7
#pragma unroll
    for (int cr = 0; cr < 2; ++cr) {
      int ch = ch0 + cr * 64;
      float w0 = convw[ch * 3 + 0], w1 = convw[ch * 3 + 1], w2 = convw[ch * 3 + 2];
      float cb = convb[ch];
      float a = (float)CH2h[(lbq * 8 + 0) * C2H + ch];
      float b = (float)CH2h[(lbq * 8 + 1) * C2H + ch];
      f16x8 out;
#pragma unroll
      for (int j = 0; j < 8; ++j) {
        float cn = (float)CH2h[(lbq * 8 + j + 2) * C2H + ch];
        out[j] = (_Float16)silu_(a * w0 + b * w1 + cn * w2 + cb);
        a = b; b = cn;
      }
      if (cr == 0) *(f16x8*)&xst[ch0 * TTS + lbq * 8] = out;
      else         *(f16x8*)&Bt[ch0 * TTS + lbq * 8] = out;
    }
    int l = t >> 3, h = t & 7;
    float raw = 0.f;
#pragma unroll
    for (int dm = 0; dm < 32; ++dm)
      raw += (float)ur_h[(l + 2) * URH + dm] * Win[dm * DPROJ + 256 + h];
    dtraw[l * 8 + h] = raw;
  }
  __syncthreads();

  // ---- P3: dt softplus + prefix scan (parallel; 32-lane Kogge-Stone) + cdec ----
  {
    const int l = t & 31, h = t >> 5;
    float raw = dtraw[l * 8 + h] + dtbias[h];
    float dt = (raw > 20.f) ? raw : log1pf(__expf(raw));
    float x = dt;
#pragma unroll
    for (int d = 1; d < 32; d <<= 1) {
      float y = __shfl_up(x, d, 32);
      if (l >= d) x += y;
    }
    const float A = -__expf(Alog[h]);
    dtv[t] = dt;
    acs[t] = A * x;
    if (l == 31) cdec[(sq * NCHUNK + c) * 8 + h] = __expf(A * x);
  }
  __syncthreads();

  // ---- P4: wv2; build A[hp][l] = wv2[h][l]*xs[l][hp] (fp16, overlay) ----
  {
    int h = t >> 5;
    wv2[t] = __expf(acs[h * 32 + 31] - acs[t]) * dtv[t];
  }
  __syncthreads();
  {
    const int hp = t >> 2, lb2 = (t & 3) * 8;
    const float* w = &wv2[(hp >> 3) * 32 + lb2];
    const _Float16* xr = &xst[hp * TTS + lb2];
    f16x8 ov;
#pragma unroll
    for (int i = 0; i < 8; ++i) ov[i] = (_Float16)((float)xr[i] * w[i]);
    *(f16x8*)&Ah[hp * TTS + lb2] = ov;
  }
  __syncthreads();

  // ---- P5: states MFMA S[hp][n] = A·B -> Sout, then coalesced global store ----
  {
    const int mt = wvi;
    f16x8 aS = *(const f16x8*)&Ah[(mt * 16 + c16) * TTS + g * 8];
#pragma unroll
    for (int nt = 0; nt < 4; ++nt) {
      f16x8 bS = *(const f16x8*)&Bt[(nt * 16 + c16) * TTS + g * 8];
      f32x4 acc = __builtin_amdgcn_mfma_f32_16x16x32_f16(aS, bS, zero4, 0, 0, 0);
#pragma unroll
      for (int r = 0; r < 4; ++r)
        Sout[(mt * 16 + 4 * g + r) * 72 + nt * 16 + c16] = __float2half(acc[r]);
    }
  }
  __syncthreads();
  const size_t sbase = (size_t)(sq * NCHUNK + c) * 4096;
#pragma unroll
  for (int i = 0; i < 2; ++i) {
    int idx = i * 256 + t;
    int hp = idx >> 3, part = idx & 7;
    *(uint4*)(S + sbase + hp * 64 + part * 8) = *(const uint4*)&Sout[hp * 72 + part * 8];
  }
}

// ---------------- K3: in-place exclusive scan over chunks (4-deep prefetch, uint2) ----------------
__global__ __launch_bounds__(128) void k3_scan(__half* __restrict__ S,
                                               const float* __restrict__ cdec) {
  __shared__ float cd[NCHUNK];
  const int sq = blockIdx.x >> 3, h = blockIdx.x & 7, t = threadIdx.x;
  for (int i = t; i < NCHUNK; i += 128) cd[i] = cdec[(sq * NCHUNK + i) * 8 + h];
  __syncthreads();
  __half* p = S + (size_t)sq * NCHUNK * 4096 + h * 512 + t * 4;
  uint2 f0 = *(const uint2*)(p);
  uint2 f1 = *(const uint2*)(p + 4096);
  uint2 f2 = *(const uint2*)(p + 2 * 4096);
  uint2 f3 = *(const uint2*)(p + 3 * 4096);
  float car0 = 0.f, car1 = 0.f, car2 = 0.f, car3 = 0.f;
  for (int c = 0; c < NCHUNK; c += 4) {
#define K3_STEP(F, K)                                                              \
    {                                                                              \
      half2_t lo = *(half2_t*)&F.x, hi = *(half2_t*)&F.y;                          \
      float s0 = (float)lo.x, s1 = (float)lo.y, s2 = (float)hi.x, s3 = (float)hi.y;\
      int nc = c + K + 4; if (nc > NCHUNK - 1) nc = NCHUNK - 1;                    \
      F = *(const uint2*)(p + (size_t)nc * 4096);                                  \
      half2_t olo, ohi;                                                            \
      olo.x = (_Float16)car0; olo.y = (_Float16)car1;                              \
      ohi.x = (_Float16)car2; ohi.y = (_Float16)car3;                              \
      uint2 ov; ov.x = *(u32*)&olo; ov.y = *(u32*)&ohi;                            \
      *(uint2*)(p + (size_t)(c + K) * 4096) = ov;                                  \
      float d = cd[c + K];                                                         \
      car0 = car0 * d + s0; car1 = car1 * d + s1;                                  \
      car2 = car2 * d + s2; car3 = car3 * d + s3;                                  \
    }
    K3_STEP(f0, 0)
    K3_STEP(f1, 1)
    K3_STEP(f2, 2)
    K3_STEP(f3, 3)
#undef K3_STEP
  }
}

// ---------------- K4: output pass — MFMA for inproj/z/G/Yd/Yo/Wout ----------------
// MFMA 16x16x32 f16 conventions (gfx950), verified R2:
//   A frag: lane holds A[row = lane&15][k = (lane>>4)*8 + j], j=0..7
//   B frag: lane holds B[k = (lane>>4)*8 + j][col = lane&15]
//   D frag: lane reg r holds D[row = 4*(lane>>4)+r][col = lane&15]
__global__ __launch_bounds__(256, 4) void k4_out(
    const __half* __restrict__ u, const float* __restrict__ Win,
    const float* __restrict__ convw, const float* __restrict__ convb,
    const float* __restrict__ dtbias, const float* __restrict__ Alog,
    const float* __restrict__ Dp, const float* __restrict__ rmsw,
    const float* __restrict__ Wout, const float* __restrict__ skip,
    const __half* __restrict__ S, __half* __restrict__ ym) {
  __shared__ __align__(16) _Float16 ur_h[48 * URH];   // 3840 B; overlays scl f32[32] after P2
  __shared__ __align__(16) _Float16 CHh[34 * CHH];    // 13872 B; overlay after conv:
                                                      //   pv fp16 [64][72] @byte 0    (9216 B)
                                                      //   G  f32  [32][36] @byte 9216 (4608 B) -> RMS partials
  __shared__ __align__(16) __half xch[32 * XC4];      // 13312 B; cols 0..63 xs, 64..127 B->ybuf, 128..191 C
  __shared__ __align__(16) float dtraw[256];          // dtraw [l][h]; later eac[h*32+l]
  __shared__ __align__(16) float dtv[256], acs[256];
  __shared__ __align__(16) _Float16 zbuf[32 * ZBS];   // 4224 B
  const int c = blockIdx.x, sq = blockIdx.y, t = threadIdx.x;
  const int l0 = c * 32;
  const int lane = t & 63, wvi = t >> 6, g = lane >> 4, c16 = lane & 15;
  const size_t ubase = (size_t)sq * (LSEQ * DM);
  const f32x4 zero4 = {0.f, 0.f, 0.f, 0.f};

  // ---- P0: stage ur (fp16), load B-frags (Win via L2), prefetch S into regs ----
  const size_t sbase = (size_t)(sq * NCHUNK + c) * 4096;
  uint4 sv0, sv1;
  {
    const uint4* sp = (const uint4*)(S + sbase);
    sv0 = sp[t * 2];
    sv1 = sp[t * 2 + 1];
  }
  for (int idx = t; idx < 48 * 32; idx += 256) {
    int r = idx >> 5, dm = idx & 31;
    int l = l0 - 2 + r;
    _Float16 v = (_Float16)0.f;
    if (r < 34 && l >= 0) v = ((const _Float16*)u)[ubase + (size_t)l * DM + dm];
    ur_h[r * URH + dm] = v;
  }
  f16x8 bfr[3];  // inproj N-tiles nt = wvi, wvi+4, wvi+8  (channels nt*16.., Win col 64+..)
#pragma unroll
  for (int i = 0; i < 3; ++i) {
    int col = 64 + (wvi + i * 4) * 16 + c16;
#pragma unroll
    for (int j = 0; j < 8; ++j) bfr[i][j] = (_Float16)Win[(g * 8 + j) * DPROJ + col];
  }
  f16x8 bz;  // z N-tile: cols wvi*16..
  {
    int col = wvi * 16 + c16;
#pragma unroll
    for (int j = 0; j < 8; ++j) bz[j] = (_Float16)Win[(g * 8 + j) * DPROJ + col];
  }
  __syncthreads();

  // ---- P1: MFMA inproj -> CHh (fp16), z -> zbuf ----
  {
    f16x8 am[3];
#pragma unroll
    for (int mt = 0; mt < 3; ++mt)
      am[mt] = *(const f16x8*)&ur_h[(mt * 16 + c16) * URH + g * 8];
#pragma unroll
    for (int i = 0; i < 3; ++i) {
      int colc = (wvi + i * 4) * 16 + c16;
#pragma unroll
      for (int mt = 0; mt < 3; ++mt) {
        f32x4 acc = __builtin_amdgcn_mfma_f32_16x16x32_f16(am[mt], bfr[i], zero4, 0, 0, 0);
#pragma unroll
        for (int r = 0; r < 4; ++r) {
          int R = mt * 16 + 4 * g + r;
          if (R < 34) CHh[R * CHH + colc] = (_Float16)acc[r];
        }
      }
    }
#pragma unroll
    for (int mz = 0; mz < 2; ++mz) {
      f16x8 az = *(const f16x8*)&ur_h[(2 + mz * 16 + c16) * URH + g * 8];
      f32x4 acc = __builtin_amdgcn_mfma_f32_16x16x32_f16(az, bz, zero4, 0, 0, 0);
#pragma unroll
      for (int r = 0; r < 4; ++r) {
        int lY = mz * 16 + 4 * g + r;
        zbuf[lY * ZBS + wvi * 16 + c16] = (_Float16)acc[r];
      }
    }
  }
  __syncthreads();

  // ---- P2: conv+silu -> xch (rolling 3-tap over 8 consecutive rows);
  //          dtraw via f32 scalar dot (precision-sensitive) ----
  {
    const int ch0 = t & 63, lbq = t >> 6;  // rows lbq*8 .. lbq*8+7
#pragma unroll
    for (int cr = 0; cr < 3; ++cr) {
      int ch = ch0 + cr * 64;
      float w0 = convw[ch * 3 + 0], w1 = convw[ch * 3 + 1], w2 = convw[ch * 3 + 2];
      float cb = convb[ch];
      float a = (float)CHh[(lbq * 8 + 0) * CHH + ch];
      float b = (float)CHh[(lbq * 8 + 1) * CHH + ch];
#pragma unroll
      for (int j = 0; j < 8; ++j) {
        float cn = (float)CHh[(lbq * 8 + j + 2) * CHH + ch];
        float v = a * w0 + b * w1 + cn * w2 + cb;
        xch[(lbq * 8 + j) * XC4 + ch] = __float2half(silu_(v));
        a = b; b = cn;
      }
    }
    int l = t >> 3, h = t & 7;
    float raw = 0.f;
#pragma unroll
    for (int dm = 0; dm < 32; ++dm)
      raw += (float)ur_h[(l + 2) * URH + dm] * Win[dm * DPROJ + 256 + h];
    dtraw[l * 8 + h] = raw;
  }
  __syncthreads();

  // ---- P3: pv <- S regs (CHh overlay); dt softplus + parallel prefix scan ----
  {
    char* pvb = (char*)CHh;
    int hp = t >> 2, part = t & 3;
    *(uint4*)(pvb + hp * 144 + part * 32) = sv0;
    *(uint4*)(pvb + hp * 144 + part * 32 + 16) = sv1;
  }
  {
    const int l = t & 31, h = t >> 5;
    float raw = dtraw[l * 8 + h] + dtbias[h];
    float dt = (raw > 20.f) ? raw : log1pf(__expf(raw));
    float x = dt;
#pragma unroll
    for (int d = 1; d < 32; d <<= 1) {
      float y = __shfl_up(x, d, 32);
      if (l >= d) x += y;
    }
    dtv[t] = dt;
    acs[t] = -__expf(Alog[h]) * x;
  }
  __syncthreads();

  // ---- P4: eac table; G = C·B^T via MFMA (stride GS=36, 16B-aligned rows) ----
  float* Gm = (float*)((char*)CHh + 9216);
  {
    float ev = __expf(acs[t]);
    dtraw[t] = ev;  // eac[h*32+l]
    const int mt = wvi >> 1, nt = wvi & 1;
    f32x4 acc = zero4;
#pragma unroll
    for (int kk = 0; kk < 2; ++kk) {
      f16x8 aC = *(const f16x8*)&xch[(mt * 16 + c16) * XC4 + 128 + kk * 32 + g * 8];
      f16x8 bB = *(const f16x8*)&xch[(nt * 16 + c16) * XC4 + 64 + kk * 32 + g * 8];
      acc = __builtin_amdgcn_mfma_f32_16x16x32_f16(aC, bB, acc, 0, 0, 0);
    }
#pragma unroll
    for (int r = 0; r < 4; ++r)
      Gm[(mt * 16 + 4 * g + r) * GS + nt * 16 + c16] = acc[r];
  }
  __syncthreads();

  // ---- P5: Yd via MFMA — build masked M-fragments in registers ----
  // M_h[row][s2] = (s2<=row) ? G[row][s2]*exp(acs_row - acs_s2)*dtv[s2] : 0
  // wave wvi handles heads 2wvi, 2wvi+1; D cols 8..15 are duplicates (discarded)
  {
    const int s2b = g * 8;
    float gv[2][8];
#pragma unroll
    for (int mt = 0; mt < 2; ++mt) {
      const float* gr = &Gm[(mt * 16 + c16) * GS + s2b];
      float4 g0 = *(const float4*)gr;
      float4 g1 = *(const float4*)(gr + 4);
      gv[mt][0] = g0.x; gv[mt][1] = g0.y; gv[mt][2] = g0.z; gv[mt][3] = g0.w;
      gv[mt][4] = g1.x; gv[mt][5] = g1.y; gv[mt][6] = g1.z; gv[mt][7] = g1.w;
    }
#pragma unroll
    for (int hh = 0; hh < 2; ++hh) {
      const int h = 2 * wvi + hh;
      const float* ap = &acs[h * 32 + s2b];
      const float* dp = &dtv[h * 32 + s2b];
      float4 a0 = *(const float4*)ap, a1 = *(const float4*)(ap + 4);
      float4 d0 = *(const float4*)dp, d1 = *(const float4*)(dp + 4);
      const float av[8] = {a0.x, a0.y, a0.z, a0.w, a1.x, a1.y, a1.z, a1.w};
      const float dv[8] = {d0.x, d0.y, d0.z, d0.w, d1.x, d1.y, d1.z, d1.w};
      f16x8 bfr2;
#pragma unroll
      for (int j = 0; j < 8; ++j)
        bfr2[j] = *(const _Float16*)&xch[(s2b + j) * XC4 + h * 8 + (c16 & 7)];
#pragma unroll
      for (int mt = 0; mt < 2; ++mt) {
        const int row = mt * 16 + c16;
        const float arow = acs[h * 32 + row];
        f16x8 afr;
#pragma unroll
        for (int j = 0; j < 8; ++j) {
          float m = gv[mt][j] * __expf(arow - av[j]) * dv[j];
          afr[j] = (_Float16)((s2b + j <= row) ? m : 0.f);
        }
        f32x4 dacc = __builtin_amdgcn_mfma_f32_16x16x32_f16(afr, bfr2, zero4, 0, 0, 0);
        if (c16 < 8) {
#pragma unroll
          for (int r = 0; r < 4; ++r)
            xch[(mt * 16 + 4 * g + r) * XC4 + 64 + h * 8 + c16] = __float2half(dacc[r]);
        }
      }
    }
  }
  __syncthreads();

  // ---- P6: Yo = C·PV^T via MFMA, scaled by eac, accumulated into ybuf ----
  {
    const __half* pvh = (const __half*)CHh;  // [64][72] fp16
#pragma unroll
    for (int mt = 0; mt < 2; ++mt) {
      f32x4 acc = zero4;
#pragma unroll
      for (int kk = 0; kk < 2; ++kk) {
        f16x8 aC = *(const f16x8*)&xch[(mt * 16 + c16) * XC4 + 128 + kk * 32 + g * 8];
        f16x8 bP = *(const f16x8*)&pvh[(wvi * 16 + c16) * 72 + kk * 32 + g * 8];
        acc = __builtin_amdgcn_mfma_f32_16x16x32_f16(aC, bP, acc, 0, 0, 0);
      }
      int hp = wvi * 16 + c16;
#pragma unroll
      for (int r = 0; r < 4; ++r) {
        int l = mt * 16 + 4 * g + r;
        float e = dtraw[(hp >> 3) * 32 + l];
        __half* yb = &xch[l * XC4 + 64 + hp];
        *yb = __float2half(__half2float(*yb) + acc[r] * e);
      }
    }
  }
  __syncthreads();

  // ---- P7: +D*xs, gate with silu(z) from zbuf ----
  {
    const int hp = t & 63;
    const float dcoef = Dp[hp >> 3];
#pragma unroll
    for (int k = 0; k < 8; ++k) {
      int l = (k * 256 + t) >> 6;
      float y = __half2float(xch[l * XC4 + 64 + hp]) + (float)xch[l * XC4 + hp] * dcoef;
      float z = (float)zbuf[l * ZBS + hp];
      y *= z / (1.f + __expf(-z));
      xch[l * XC4 + 64 + hp] = __float2half(y);
    }
  }
  __syncthreads();

  // ---- P8: RMS scale factors (two-stage parallel reduce) ----
  float* rp = Gm;                  // [32][9] partials (G dead after P5)
  float* scl = (float*)ur_h;       // ur dead after P2
  {
    const int l = t & 31, seg = t >> 5;
    float p = 0.f;
#pragma unroll
    for (int k = 0; k < 8; ++k) {
      float v = __half2float(xch[l * XC4 + 64 + seg * 8 + k]);
      p += v * v;
    }
    rp[l * 9 + seg] = p;
  }
  __syncthreads();
  if (t < 32) {
    float s2s = 0.f;
#pragma unroll
    for (int seg = 0; seg < 8; ++seg) s2s += rp[t * 9 + seg];
    scl[t] = rsqrtf(s2s * (1.f / 64.f) + 1e-5f);
  }
  __syncthreads();

  // ---- P9: apply rms * rmsw ----
  for (int idx = t; idx < 2048; idx += 256) {
    int l = idx >> 6, hp = idx & 63;
    xch[l * XC4 + 64 + hp] =
        __float2half(__half2float(xch[l * XC4 + 64 + hp]) * scl[l] * rmsw[hp]);
  }
  __syncthreads();

  // ---- P10: y @ Wout via MFMA + skip, store ym ----
  {
    const float skipv = skip[0];
    const int mt = wvi >> 1, nt = wvi & 1;
    f32x4 acc = zero4;
#pragma unroll
    for (int kk = 0; kk < 2; ++kk) {
      f16x8 aY = *(const f16x8*)&xch[(mt * 16 + c16) * XC4 + 64 + kk * 32 + g * 8];
      f16x8 bW;
#pragma unroll
      for (int j = 0; j < 8; ++j)
        bW[j] = (_Float16)Wout[(kk * 32 + g * 8 + j) * 32 + nt * 16 + c16];
      acc = __builtin_amdgcn_mfma_f32_16x16x32_f16(aY, bW, acc, 0, 0, 0);
    }
#pragma unroll
    for (int r = 0; r < 4; ++r) {
      int l = mt * 16 + 4 * g + r;
      int dm = nt * 16 + c16;
      size_t gi = ubase + (size_t)(l0 + l) * DM + dm;
      ym[gi] = __float2half(acc[r] + skipv * __half2float(u[gi]));
    }
  }
}

// ---------------- K5: regroup + LN2 + proj(256x256) via MFMA + transpose ----------------
__global__ __launch_bounds__(256, 4) void k5_ln_proj(const __half* __restrict__ ym,
                                                     const float* __restrict__ lnw,
                                                     const float* __restrict__ lnb,
                                                     const float* __restrict__ pw,
                                                     const float* __restrict__ pb,
                                                     float* __restrict__ outp) {
  __shared__ __align__(16) char buf[33792];  // phase A: yh fp16 [32][YH5] (16896 B)
                                             // phase B: res f32 [256][33] (33792 B)
  __shared__ float mu[32], rs[32], wv[256], bv[256];
  __shared__ float ps[32 * 9], ps2[32 * 9];
  _Float16* yh = (_Float16*)buf;
  float* res = (float*)buf;
  const int b = blockIdx.y, l0 = blockIdx.x * 32, t = threadIdx.x;
  const int lane = t & 63, wvi = t >> 6, g = lane >> 4, c16 = lane & 15;
  const f32x4 zero4 = {0.f, 0.f, 0.f, 0.f};
  wv[t] = lnw[t];
  bv[t] = lnb[t];
  // ---- load ym -> yh fp16 [ll][sp*32+dm] (half2 moves) ----
  for (int sp = 0; sp < 8; ++sp) {
#pragma unroll
    for (int i = 0; i < 2; ++i) {
      int idx = i * 256 + t;
      int ll = idx >> 4, dmp = (idx & 15) * 2;
      u32 v = *(const u32*)&ym[(((size_t)(sp * B0N + b)) * LSEQ + l0 + ll) * DM + dmp];
      *(u32*)&yh[ll * YH5 + sp * 32 + dmp] = v;
    }
  }
  __syncthreads();
  // ---- LN stats (two-stage parallel) ----
  {
    const int ll = t & 31, seg = t >> 5;
    float s = 0.f, s2 = 0.f;
#pragma unroll 8
    for (int i = 0; i < 32; ++i) {
      float v = (float)yh[ll * YH5 + seg * 32 + i];
      s += v; s2 += v * v;
    }
    ps[ll * 9 + seg] = s;
    ps2[ll * 9 + seg] = s2;
  }
  __syncthreads();
  if (t < 32) {
    float s = 0.f, s2 = 0.f;
#pragma unroll
    for (int seg = 0; seg < 8; ++seg) { s += ps[t * 9 + seg]; s2 += ps2[t * 9 + seg]; }
    float m = s * (1.f / 256.f);
    mu[t] = m;
    rs[t] = rsqrtf(s2 * (1.f / 256.f) - m * m + 1e-5f);
  }
  __syncthreads();
  // ---- LN apply in place (fp16) ----
#pragma unroll
  for (int i = 0; i < 32; ++i) {
    int idx = i * 256 + t;
    int ll = idx >> 8, ch = idx & 255;
    float v = ((float)yh[ll * YH5 + ch] - mu[ll]) * rs[ll] * wv[ch] + bv[ch];
    yh[ll * YH5 + ch] = (_Float16)v;
  }
  __syncthreads();
  // ---- hoist A-frags to registers (16 x f16x8), then overlay res ----
  f16x8 am[16];
#pragma unroll
  for (int mt = 0; mt < 2; ++mt)
#pragma unroll
    for (int kk = 0; kk < 8; ++kk)
      am[mt * 8 + kk] = *(const f16x8*)&yh[(mt * 16 + c16) * YH5 + kk * 32 + g * 8];
  __syncthreads();  // all yh reads complete; buf becomes res
  // ---- proj GEMM: wave wvi owns n-tiles wvi, wvi+4, wvi+8, wvi+12 ----
#pragma unroll
  for (int ni = 0; ni < 4; ++ni) {
    const int col = (wvi + ni * 4) * 16 + c16;
    f32x4 acc0 = zero4, acc1 = zero4;
#pragma unroll
    for (int kk = 0; kk < 8; ++kk) {
      f16x8 bW;
#pragma unroll
      for (int j = 0; j < 8; ++j)
        bW[j] = (_Float16)pw[(size_t)(kk * 32 + g * 8 + j) * 256 + col];
      acc0 = __builtin_amdgcn_mfma_f32_16x16x32_f16(am[kk], bW, acc0, 0, 0, 0);
      acc1 = __builtin_amdgcn_mfma_f32_16x16x32_f16(am[8 + kk], bW, acc1, 0, 0, 0);
    }
    const float bias = pb[col];
#pragma unroll
    for (int r = 0; r < 4; ++r) {
      res[col * 33 + 4 * g + r] = acc0[r] + bias;
      res[col * 33 + 16 + 4 * g + r] = acc1[r] + bias;
    }
  }
  __syncthreads();
  // ---- store (transpose to NCHW) ----
  for (int idx = t; idx < 8192; idx += 256) {
    int o = idx >> 5, l = idx & 31;
    outp[((size_t)(b * 256 + o)) * LSEQ + l0 + l] = res[o * 33 + l];
  }
}

extern "C" void kernel_launch(void* const* d_in, const int* in_sizes, int n_in,
                              void* d_out, int out_size, void* d_ws, size_t ws_size,
                              hipStream_t stream) {
  (void)in_sizes; (void)n_in; (void)out_size;
  const float* x     = (const float*)d_in[0];
  const float* lnw   = (const float*)d_in[1];
  const float* lnb   = (const float*)d_in[2];
  const float* skip  = (const float*)d_in[3];
  const float* pw    = (const float*)d_in[4];
  const float* pb    = (const float*)d_in[5];
  const float* Win   = (const float*)d_in[6];
  const float* convw = (const float*)d_in[7];
  const float* convb = (const float*)d_in[8];
  const float* dtb   = (const float*)d_in[9];
  const float* Alog  = (const float*)d_in[10];
  const float* Dp    = (const float*)d_in[11];
  const float* rmsw  = (const float*)d_in[12];
  const float* Wout  = (const float*)d_in[13];
  float* outp = (float*)d_out;

  // workspace layout (fp16 tensors): total 227,082,240 B (ws cap proven < 491 MB in R1)
  const size_t NEED = 227082240ull;
  if (ws_size < NEED) return;
  char* ws = (char*)d_ws;
  __half* u    = (__half*)ws;                    //  37,748,736 B
  __half* S    = (__half*)(ws + 37748736);       // 150,994,944 B
  float*  cdec = (float*)(ws + 188743680);       //     589,824 B
  __half* ym   = (__half*)(ws + 189333504);      //  37,748,736 B

  k1_ln_split<<<dim3(288, 8), 256, 0, stream>>>(x, lnw, lnb, u);
  k2_states<<<dim3(288, 64), 256, 0, stream>>>(u, Win, convw, convb, dtb, Alog, S, cdec);
  k3_scan<<<dim3(512), 128, 0, stream>>>(S, cdec);
  k4_out<<<dim3(288, 64), 256, 0, stream>>>(u, Win, convw, convb, dtb, Alog, Dp, rmsw,
                                            Wout, skip, S, ym);
  k5_ln_proj<<<dim3(288, 8), 256, 0, stream>>>(ym, lnw, lnb, pw, pb, outp);
}

// Round 8
// 630.974 us; speedup vs baseline: 1.0117x; 1.0117x over previous
//
#include <hip/hip_runtime.h>
#include <hip/hip_fp16.h>
#include <math.h>

typedef unsigned short u16;
typedef unsigned int u32;
typedef _Float16 half2_t __attribute__((ext_vector_type(2)));
typedef _Float16 f16x8 __attribute__((ext_vector_type(8)));
typedef float f32x4 __attribute__((ext_vector_type(4)));

#define B0N 8
#define LSEQ 9216
#define NSEQ 64
#define NCHUNK 288
#define DM 32
#define DPROJ 264
#define CONVCH 192
#define XC4 208   // k4 xc row stride (fp16, 416B rows -> 16B-aligned for ds_read_b128)
#define URH 40    // ur row stride (fp16, 80B rows -> 16B-aligned, 2-way banks)
#define CHH 204   // k4 CH row stride (fp16)
#define ZBS 66    // k4 zbuf row stride (fp16)
#define C2H 132   // k2 CH row stride (fp16, 264B rows; conv reads are scalar)
#define TTS 40    // k2 transposed xs/B/A row stride (fp16, 80B rows)
#define GS 36     // k4 G row stride (f32, 144B rows -> 16B-aligned)
#define YH5 264   // k5 yh row stride (fp16, 528B rows -> 16B-aligned)

#ifndef __has_builtin
#define __has_builtin(x) 0
#endif

__device__ __forceinline__ float silu_(float v) { return v / (1.f + __expf(-v)); }

// ---------------- K1: LayerNorm(256) + split -> u (64,9216,32) fp16 ----------------
__global__ __launch_bounds__(256) void k1_ln_split(const float* __restrict__ x,
                                                   const float* __restrict__ lnw,
                                                   const float* __restrict__ lnb,
                                                   __half* __restrict__ u) {
  __shared__ float tile[256 * 33];  // [c][ll]
  __shared__ float mu[32], rs[32], wv[256], bv[256];
  __shared__ float ps[32 * 9], ps2[32 * 9];
  const int b = blockIdx.y, l0 = blockIdx.x * 32, t = threadIdx.x;
  wv[t] = lnw[t];
  bv[t] = lnb[t];
#pragma unroll
  for (int i = 0; i < 8; ++i) {
    int idx = i * 256 + t;
    int cc = idx >> 3, part = idx & 7;
    float4 v = *(const float4*)&x[((size_t)b * 256 + cc) * LSEQ + l0 + part * 4];
    tile[cc * 33 + part * 4 + 0] = v.x;
    tile[cc * 33 + part * 4 + 1] = v.y;
    tile[cc * 33 + part * 4 + 2] = v.z;
    tile[cc * 33 + part * 4 + 3] = v.w;
  }
  __syncthreads();
  {
    const int ll = t & 31, seg = t >> 5;
    float s = 0.f, s2 = 0.f;
#pragma unroll 8
    for (int i = 0; i < 32; ++i) {
      float v = tile[(seg * 32 + i) * 33 + ll];
      s += v; s2 += v * v;
    }
    ps[ll * 9 + seg] = s;
    ps2[ll * 9 + seg] = s2;
  }
  __syncthreads();
  if (t < 32) {
    float s = 0.f, s2 = 0.f;
#pragma unroll
    for (int seg = 0; seg < 8; ++seg) { s += ps[t * 9 + seg]; s2 += ps2[t * 9 + seg]; }
    float m = s * (1.f / 256.f);
    mu[t] = m;
    rs[t] = rsqrtf(s2 * (1.f / 256.f) - m * m + 1e-5f);
  }
  __syncthreads();
#pragma unroll 4
  for (int i = 0; i < 32; ++i) {
    int sp = i >> 2, sub = i & 3;
    int ll = sub * 8 + (t >> 5), dm = t & 31;
    int c = sp * 32 + dm;
    float v = (tile[c * 33 + ll] - mu[ll]) * rs[ll] * wv[c] + bv[c];
    u[(((size_t)(sp * B0N + b)) * LSEQ + l0 + ll) * DM + dm] = __float2half(v);
  }
}

// ---------------- K2: in-proj + conv + dt + per-chunk states (MFMA, fp16 CH) ----------------
// LDS arena (32512 B):
//   ur_h  [48][URH] fp16 @ 0      (3840 B)
//   CH2h  [34][C2H] fp16 @ 3840   (8976 B)   dead after conv
//   Ah    [64][TTS] fp16 @ 3840   (5120 B)   overlay (inside CH2h region)
//   Sout  [64][72]  fp16 @ 8960   (9216 B)   overlay (CH2h tail; disjoint from Ah)
//   xst   [64][TTS] fp16 @ 18176  (5120 B)
//   Bt    [64][TTS] fp16 @ 23296  (5120 B)
//   dtraw/dtv/acs/wv2 f32[256] @ 28416..32512
__global__ __launch_bounds__(256, 4) void k2_states(
    const __half* __restrict__ u, const float* __restrict__ Win,
    const float* __restrict__ convw, const float* __restrict__ convb,
    const float* __restrict__ dtbias, const float* __restrict__ Alog,
    __half* __restrict__ S, float* __restrict__ cdec) {
  __shared__ __align__(16) char smem[32512];
  _Float16* ur_h = (_Float16*)smem;
  _Float16* CH2h = (_Float16*)(smem + 3840);
  _Float16* Ah   = (_Float16*)(smem + 3840);
  __half*   Sout = (__half*)(smem + 8960);
  _Float16* xst  = (_Float16*)(smem + 18176);
  _Float16* Bt   = (_Float16*)(smem + 23296);
  float* dtraw = (float*)(smem + 28416);
  float* dtv   = (float*)(smem + 29440);
  float* acs   = (float*)(smem + 30464);
  float* wv2   = (float*)(smem + 31488);
  const int c = blockIdx.x, sq = blockIdx.y, t = threadIdx.x;
  const int l0 = c * 32;
  const int lane = t & 63, wvi = t >> 6, g = lane >> 4, c16 = lane & 15;
  const size_t ubase = (size_t)sq * (LSEQ * DM);
  const f32x4 zero4 = {0.f, 0.f, 0.f, 0.f};

  // ---- P0: stage ur (fp16); load Win B-frags (cols 64..191 -> channels 0..127) ----
  for (int idx = t; idx < 48 * 32; idx += 256) {
    int r = idx >> 5, dm = idx & 31;
    int l = l0 - 2 + r;
    _Float16 v = (_Float16)0.f;
    if (r < 34 && l >= 0) v = ((const _Float16*)u)[ubase + (size_t)l * DM + dm];
    ur_h[r * URH + dm] = v;
  }
  f16x8 bfr[2];  // N-tiles nt = wvi, wvi+4
#pragma unroll
  for (int i = 0; i < 2; ++i) {
    int col = 64 + (wvi + i * 4) * 16 + c16;
#pragma unroll
    for (int j = 0; j < 8; ++j) bfr[i][j] = (_Float16)Win[(g * 8 + j) * DPROJ + col];
  }
  __syncthreads();

  // ---- P1: MFMA inproj -> CH2h (34 rows x 128 channels, fp16) ----
  {
    f16x8 am[3];
#pragma unroll
    for (int mt = 0; mt < 3; ++mt)
      am[mt] = *(const f16x8*)&ur_h[(mt * 16 + c16) * URH + g * 8];
#pragma unroll
    for (int i = 0; i < 2; ++i) {
      int colc = (wvi + i * 4) * 16 + c16;
#pragma unroll
      for (int mt = 0; mt < 3; ++mt) {
        f32x4 acc = __builtin_amdgcn_mfma_f32_16x16x32_f16(am[mt], bfr[i], zero4, 0, 0, 0);
#pragma unroll
        for (int r = 0; r < 4; ++r) {
          int R = mt * 16 + 4 * g + r;
          if (R < 34) CH2h[R * C2H + colc] = (_Float16)acc[r];
        }
      }
    }
  }
  __syncthreads();

  // ---- P2: conv+silu -> xst/Bt (rolling 3-tap, f16x8 row stores); dtraw f32 dot ----
  {
    const int ch0 = t & 63, lbq = t >> 6;  // rows lbq*8 .. lbq*8+7
#pragma unroll
    for (int cr = 0; cr < 2; ++cr) {
      int ch = ch0 + cr * 64;
      float w0 = convw[ch * 3 + 0], w1 = convw[ch * 3 + 1], w2 = convw[ch * 3 + 2];
      float cb = convb[ch];
      float a = (float)CH2h[(lbq * 8 + 0) * C2H + ch];
      float b = (float)CH2h[(lbq * 8 + 1) * C2H + ch];
      f16x8 out;
#pragma unroll
      for (int j = 0; j < 8; ++j) {
        float cn = (float)CH2h[(lbq * 8 + j + 2) * C2H + ch];
        out[j] = (_Float16)silu_(a * w0 + b * w1 + cn * w2 + cb);
        a = b; b = cn;
      }
      if (cr == 0) *(f16x8*)&xst[ch0 * TTS + lbq * 8] = out;
      else         *(f16x8*)&Bt[ch0 * TTS + lbq * 8] = out;
    }
    int l = t >> 3, h = t & 7;
    float raw = 0.f;
#pragma unroll
    for (int dm = 0; dm < 32; ++dm)
      raw += (float)ur_h[(l + 2) * URH + dm] * Win[dm * DPROJ + 256 + h];
    dtraw[l * 8 + h] = raw;
  }
  __syncthreads();

  // ---- P3: dt softplus + prefix scan (parallel; 32-lane Kogge-Stone) + cdec ----
  {
    const int l = t & 31, h = t >> 5;
    float raw = dtraw[l * 8 + h] + dtbias[h];
    float dt = (raw > 20.f) ? raw : log1pf(__expf(raw));
    float x = dt;
#pragma unroll
    for (int d = 1; d < 32; d <<= 1) {
      float y = __shfl_up(x, d, 32);
      if (l >= d) x += y;
    }
    const float A = -__expf(Alog[h]);
    dtv[t] = dt;
    acs[t] = A * x;
    if (l == 31) cdec[(sq * NCHUNK + c) * 8 + h] = __expf(A * x);
  }
  __syncthreads();

  // ---- P4: wv2; build A[hp][l] = wv2[h][l]*xs[l][hp] (fp16, overlay) ----
  {
    int h = t >> 5;
    wv2[t] = __expf(acs[h * 32 + 31] - acs[t]) * dtv[t];
  }
  __syncthreads();
  {
    const int hp = t >> 2, lb2 = (t & 3) * 8;
    const float* w = &wv2[(hp >> 3) * 32 + lb2];
    const _Float16* xr = &xst[hp * TTS + lb2];
    f16x8 ov;
#pragma unroll
    for (int i = 0; i < 8; ++i) ov[i] = (_Float16)((float)xr[i] * w[i]);
    *(f16x8*)&Ah[hp * TTS + lb2] = ov;
  }
  __syncthreads();

  // ---- P5: states MFMA S[hp][n] = A·B -> Sout, then coalesced global store ----
  {
    const int mt = wvi;
    f16x8 aS = *(const f16x8*)&Ah[(mt * 16 + c16) * TTS + g * 8];
#pragma unroll
    for (int nt = 0; nt < 4; ++nt) {
      f16x8 bS = *(const f16x8*)&Bt[(nt * 16 + c16) * TTS + g * 8];
      f32x4 acc = __builtin_amdgcn_mfma_f32_16x16x32_f16(aS, bS, zero4, 0, 0, 0);
#pragma unroll
      for (int r = 0; r < 4; ++r)
        Sout[(mt * 16 + 4 * g + r) * 72 + nt * 16 + c16] = __float2half(acc[r]);
    }
  }
  __syncthreads();
  const size_t sbase = (size_t)(sq * NCHUNK + c) * 4096;
#pragma unroll
  for (int i = 0; i < 2; ++i) {
    int idx = i * 256 + t;
    int hp = idx >> 3, part = idx & 7;
    *(uint4*)(S + sbase + hp * 64 + part * 8) = *(const uint4*)&Sout[hp * 72 + part * 8];
  }
}

// ---------------- K3: in-place exclusive scan (256 thr, u32 grain, 8-deep prefetch) ----------------
__global__ __launch_bounds__(256) void k3_scan(__half* __restrict__ S,
                                               const float* __restrict__ cdec) {
  __shared__ float cd[NCHUNK];
  const int sq = blockIdx.x >> 3, h = blockIdx.x & 7, t = threadIdx.x;
  for (int i = t; i < NCHUNK; i += 256) cd[i] = cdec[(sq * NCHUNK + i) * 8 + h];
  __syncthreads();
  __half* p = S + (size_t)sq * NCHUNK * 4096 + h * 512 + t * 2;
  u32 f0 = *(const u32*)(p);
  u32 f1 = *(const u32*)(p + 4096);
  u32 f2 = *(const u32*)(p + 2 * 4096);
  u32 f3 = *(const u32*)(p + 3 * 4096);
  u32 f4 = *(const u32*)(p + 4 * 4096);
  u32 f5 = *(const u32*)(p + 5 * 4096);
  u32 f6 = *(const u32*)(p + 6 * 4096);
  u32 f7 = *(const u32*)(p + 7 * 4096);
  float car0 = 0.f, car1 = 0.f;
  for (int c = 0; c < NCHUNK; c += 8) {
#define K3_STEP(F, K)                                                    \
    {                                                                    \
      half2_t s2h = *(half2_t*)&F;                                       \
      float s0 = (float)s2h.x, s1 = (float)s2h.y;                        \
      int nc = c + K + 8; if (nc > NCHUNK - 1) nc = NCHUNK - 1;          \
      F = *(const u32*)(p + (size_t)nc * 4096);                          \
      half2_t o; o.x = (_Float16)car0; o.y = (_Float16)car1;             \
      *(u32*)(p + (size_t)(c + K) * 4096) = *(u32*)&o;                   \
      float d = cd[c + K];                                               \
      car0 = car0 * d + s0; car1 = car1 * d + s1;                        \
    }
    K3_STEP(f0, 0)
    K3_STEP(f1, 1)
    K3_STEP(f2, 2)
    K3_STEP(f3, 3)
    K3_STEP(f4, 4)
    K3_STEP(f5, 5)
    K3_STEP(f6, 6)
    K3_STEP(f7, 7)
#undef K3_STEP
  }
}

// ---------------- K4: output pass — MFMA for inproj/z/G/Yd/Yo/Wout ----------------
// MFMA 16x16x32 f16 conventions (gfx950), verified R2:
//   A frag: lane holds A[row = lane&15][k = (lane>>4)*8 + j], j=0..7
//   B frag: lane holds B[k = (lane>>4)*8 + j][col = lane&15]
//   D frag: lane reg r holds D[row = 4*(lane>>4)+r][col = lane&15]
__global__ __launch_bounds__(256, 4) void k4_out(
    const __half* __restrict__ u, const float* __restrict__ Win,
    const float* __restrict__ convw, const float* __restrict__ convb,
    const float* __restrict__ dtbias, const float* __restrict__ Alog,
    const float* __restrict__ Dp, const float* __restrict__ rmsw,
    const float* __restrict__ Wout, const float* __restrict__ skip,
    const __half* __restrict__ S, __half* __restrict__ ym) {
  __shared__ __align__(16) _Float16 ur_h[48 * URH];   // 3840 B; overlays scl f32[32] after P2
  __shared__ __align__(16) _Float16 CHh[34 * CHH];    // 13872 B; overlay after conv:
                                                      //   pv fp16 [64][72] @byte 0    (9216 B)
                                                      //   G  f32  [32][36] @byte 9216 (4608 B) -> RMS partials
  __shared__ __align__(16) __half xch[32 * XC4];      // 13312 B; cols 0..63 xs, 64..127 B->ybuf, 128..191 C
  __shared__ __align__(16) float dtraw[256];          // dtraw [l][h]; later eac[h*32+l]
  __shared__ __align__(16) float dtv[256], acs[256];
  __shared__ __align__(16) _Float16 zbuf[32 * ZBS];   // 4224 B
  const int c = blockIdx.x, sq = blockIdx.y, t = threadIdx.x;
  const int l0 = c * 32;
  const int lane = t & 63, wvi = t >> 6, g = lane >> 4, c16 = lane & 15;
  const size_t ubase = (size_t)sq * (LSEQ * DM);
  const f32x4 zero4 = {0.f, 0.f, 0.f, 0.f};

  // ---- P0: stage ur (fp16), load B-frags (Win via L2), prefetch S into regs ----
  const size_t sbase = (size_t)(sq * NCHUNK + c) * 4096;
  uint4 sv0, sv1;
  {
    const uint4* sp = (const uint4*)(S + sbase);
    sv0 = sp[t * 2];
    sv1 = sp[t * 2 + 1];
  }
  for (int idx = t; idx < 48 * 32; idx += 256) {
    int r = idx >> 5, dm = idx & 31;
    int l = l0 - 2 + r;
    _Float16 v = (_Float16)0.f;
    if (r < 34 && l >= 0) v = ((const _Float16*)u)[ubase + (size_t)l * DM + dm];
    ur_h[r * URH + dm] = v;
  }
  f16x8 bfr[3];  // inproj N-tiles nt = wvi, wvi+4, wvi+8  (channels nt*16.., Win col 64+..)
#pragma unroll
  for (int i = 0; i < 3; ++i) {
    int col = 64 + (wvi + i * 4) * 16 + c16;
#pragma unroll
    for (int j = 0; j < 8; ++j) bfr[i][j] = (_Float16)Win[(g * 8 + j) * DPROJ + col];
  }
  f16x8 bz;  // z N-tile: cols wvi*16..
  {
    int col = wvi * 16 + c16;
#pragma unroll
    for (int j = 0; j < 8; ++j) bz[j] = (_Float16)Win[(g * 8 + j) * DPROJ + col];
  }
  __syncthreads();

  // ---- P1: MFMA inproj -> CHh (fp16), z -> zbuf ----
  {
    f16x8 am[3];
#pragma unroll
    for (int mt = 0; mt < 3; ++mt)
      am[mt] = *(const f16x8*)&ur_h[(mt * 16 + c16) * URH + g * 8];
#pragma unroll
    for (int i = 0; i < 3; ++i) {
      int colc = (wvi + i * 4) * 16 + c16;
#pragma unroll
      for (int mt = 0; mt < 3; ++mt) {
        f32x4 acc = __builtin_amdgcn_mfma_f32_16x16x32_f16(am[mt], bfr[i], zero4, 0, 0, 0);
#pragma unroll
        for (int r = 0; r < 4; ++r) {
          int R = mt * 16 + 4 * g + r;
          if (R < 34) CHh[R * CHH + colc] = (_Float16)acc[r];
        }
      }
    }
#pragma unroll
    for (int mz = 0; mz < 2; ++mz) {
      f16x8 az = *(const f16x8*)&ur_h[(2 + mz * 16 + c16) * URH + g * 8];
      f32x4 acc = __builtin_amdgcn_mfma_f32_16x16x32_f16(az, bz, zero4, 0, 0, 0);
#pragma unroll
      for (int r = 0; r < 4; ++r) {
        int lY = mz * 16 + 4 * g + r;
        zbuf[lY * ZBS + wvi * 16 + c16] = (_Float16)acc[r];
      }
    }
  }
  __syncthreads();

  // ---- P2: conv+silu -> xch (rolling 3-tap over 8 consecutive rows);
  //          dtraw via f32 scalar dot (precision-sensitive) ----
  {
    const int ch0 = t & 63, lbq = t >> 6;  // rows lbq*8 .. lbq*8+7
#pragma unroll
    for (int cr = 0; cr < 3; ++cr) {
      int ch = ch0 + cr * 64;
      float w0 = convw[ch * 3 + 0], w1 = convw[ch * 3 + 1], w2 = convw[ch * 3 + 2];
      float cb = convb[ch];
      float a = (float)CHh[(lbq * 8 + 0) * CHH + ch];
      float b = (float)CHh[(lbq * 8 + 1) * CHH + ch];
#pragma unroll
      for (int j = 0; j < 8; ++j) {
        float cn = (float)CHh[(lbq * 8 + j + 2) * CHH + ch];
        float v = a * w0 + b * w1 + cn * w2 + cb;
        xch[(lbq * 8 + j) * XC4 + ch] = __float2half(silu_(v));
        a = b; b = cn;
      }
    }
    int l = t >> 3, h = t & 7;
    float raw = 0.f;
#pragma unroll
    for (int dm = 0; dm < 32; ++dm)
      raw += (float)ur_h[(l + 2) * URH + dm] * Win[dm * DPROJ + 256 + h];
    dtraw[l * 8 + h] = raw;
  }
  __syncthreads();

  // ---- P3: pv <- S regs (CHh overlay); dt softplus + parallel prefix scan ----
  {
    char* pvb = (char*)CHh;
    int hp = t >> 2, part = t & 3;
    *(uint4*)(pvb + hp * 144 + part * 32) = sv0;
    *(uint4*)(pvb + hp * 144 + part * 32 + 16) = sv1;
  }
  {
    const int l = t & 31, h = t >> 5;
    float raw = dtraw[l * 8 + h] + dtbias[h];
    float dt = (raw > 20.f) ? raw : log1pf(__expf(raw));
    float x = dt;
#pragma unroll
    for (int d = 1; d < 32; d <<= 1) {
      float y = __shfl_up(x, d, 32);
      if (l >= d) x += y;
    }
    dtv[t] = dt;
    acs[t] = -__expf(Alog[h]) * x;
  }
  __syncthreads();

  // ---- P4: eac table; G = C·B^T via MFMA (stride GS=36, 16B-aligned rows) ----
  float* Gm = (float*)((char*)CHh + 9216);
  {
    float ev = __expf(acs[t]);
    dtraw[t] = ev;  // eac[h*32+l]
    const int mt = wvi >> 1, nt = wvi & 1;
    f32x4 acc = zero4;
#pragma unroll
    for (int kk = 0; kk < 2; ++kk) {
      f16x8 aC = *(const f16x8*)&xch[(mt * 16 + c16) * XC4 + 128 + kk * 32 + g * 8];
      f16x8 bB = *(const f16x8*)&xch[(nt * 16 + c16) * XC4 + 64 + kk * 32 + g * 8];
      acc = __builtin_amdgcn_mfma_f32_16x16x32_f16(aC, bB, acc, 0, 0, 0);
    }
#pragma unroll
    for (int r = 0; r < 4; ++r)
      Gm[(mt * 16 + 4 * g + r) * GS + nt * 16 + c16] = acc[r];
  }
  __syncthreads();

  // ---- P5: Yd via MFMA — build masked M-fragments in registers ----
  // M_h[row][s2] = (s2<=row) ? G[row][s2]*exp(acs_row - acs_s2)*dtv[s2] : 0
  // wave wvi handles heads 2wvi, 2wvi+1; D cols 8..15 are duplicates (discarded)
  {
    const int s2b = g * 8;
    float gv[2][8];
#pragma unroll
    for (int mt = 0; mt < 2; ++mt) {
      const float* gr = &Gm[(mt * 16 + c16) * GS + s2b];
      float4 g0 = *(const float4*)gr;
      float4 g1 = *(const float4*)(gr + 4);
      gv[mt][0] = g0.x; gv[mt][1] = g0.y; gv[mt][2] = g0.z; gv[mt][3] = g0.w;
      gv[mt][4] = g1.x; gv[mt][5] = g1.y; gv[mt][6] = g1.z; gv[mt][7] = g1.w;
    }
#pragma unroll
    for (int hh = 0; hh < 2; ++hh) {
      const int h = 2 * wvi + hh;
      const float* ap = &acs[h * 32 + s2b];
      const float* dp = &dtv[h * 32 + s2b];
      float4 a0 = *(const float4*)ap, a1 = *(const float4*)(ap + 4);
      float4 d0 = *(const float4*)dp, d1 = *(const float4*)(dp + 4);
      const float av[8] = {a0.x, a0.y, a0.z, a0.w, a1.x, a1.y, a1.z, a1.w};
      const float dv[8] = {d0.x, d0.y, d0.z, d0.w, d1.x, d1.y, d1.z, d1.w};
      f16x8 bfr2;
#pragma unroll
      for (int j = 0; j < 8; ++j)
        bfr2[j] = *(const _Float16*)&xch[(s2b + j) * XC4 + h * 8 + (c16 & 7)];
#pragma unroll
      for (int mt = 0; mt < 2; ++mt) {
        const int row = mt * 16 + c16;
        const float arow = acs[h * 32 + row];
        f16x8 afr;
#pragma unroll
        for (int j = 0; j < 8; ++j) {
          float m = gv[mt][j] * __expf(arow - av[j]) * dv[j];
          afr[j] = (_Float16)((s2b + j <= row) ? m : 0.f);
        }
        f32x4 dacc = __builtin_amdgcn_mfma_f32_16x16x32_f16(afr, bfr2, zero4, 0, 0, 0);
        if (c16 < 8) {
#pragma unroll
          for (int r = 0; r < 4; ++r)
            xch[(mt * 16 + 4 * g + r) * XC4 + 64 + h * 8 + c16] = __float2half(dacc[r]);
        }
      }
    }
  }
  __syncthreads();

  // ---- P6: Yo = C·PV^T via MFMA, scaled by eac, accumulated into ybuf ----
  {
    const __half* pvh = (const __half*)CHh;  // [64][72] fp16
#pragma unroll
    for (int mt = 0; mt < 2; ++mt) {
      f32x4 acc = zero4;
#pragma unroll
      for (int kk = 0; kk < 2; ++kk) {
        f16x8 aC = *(const f16x8*)&xch[(mt * 16 + c16) * XC4 + 128 + kk * 32 + g * 8];
        f16x8 bP = *(const f16x8*)&pvh[(wvi * 16 + c16) * 72 + kk * 32 + g * 8];
        acc = __builtin_amdgcn_mfma_f32_16x16x32_f16(aC, bP, acc, 0, 0, 0);
      }
      int hp = wvi * 16 + c16;
#pragma unroll
      for (int r = 0; r < 4; ++r) {
        int l = mt * 16 + 4 * g + r;
        float e = dtraw[(hp >> 3) * 32 + l];
        __half* yb = &xch[l * XC4 + 64 + hp];
        *yb = __float2half(__half2float(*yb) + acc[r] * e);
      }
    }
  }
  __syncthreads();

  // ---- P7: +D*xs, gate with silu(z) from zbuf ----
  {
    const int hp = t & 63;
    const float dcoef = Dp[hp >> 3];
#pragma unroll
    for (int k = 0; k < 8; ++k) {
      int l = (k * 256 + t) >> 6;
      float y = __half2float(xch[l * XC4 + 64 + hp]) + (float)xch[l * XC4 + hp] * dcoef;
      float z = (float)zbuf[l * ZBS + hp];
      y *= z / (1.f + __expf(-z));
      xch[l * XC4 + 64 + hp] = __float2half(y);
    }
  }
  __syncthreads();

  // ---- P8: RMS scale factors (two-stage parallel reduce) ----
  float* rp = Gm;                  // [32][9] partials (G dead after P5)
  float* scl = (float*)ur_h;       // ur dead after P2
  {
    const int l = t & 31, seg = t >> 5;
    float p = 0.f;
#pragma unroll
    for (int k = 0; k < 8; ++k) {
      float v = __half2float(xch[l * XC4 + 64 + seg * 8 + k]);
      p += v * v;
    }
    rp[l * 9 + seg] = p;
  }
  __syncthreads();
  if (t < 32) {
    float s2s = 0.f;
#pragma unroll
    for (int seg = 0; seg < 8; ++seg) s2s += rp[t * 9 + seg];
    scl[t] = rsqrtf(s2s * (1.f / 64.f) + 1e-5f);
  }
  __syncthreads();

  // ---- P9: apply rms * rmsw ----
  for (int idx = t; idx < 2048; idx += 256) {
    int l = idx >> 6, hp = idx & 63;
    xch[l * XC4 + 64 + hp] =
        __float2half(__half2float(xch[l * XC4 + 64 + hp]) * scl[l] * rmsw[hp]);
  }
  __syncthreads();

  // ---- P10: y @ Wout via MFMA + skip, store ym ----
  {
    const float skipv = skip[0];
    const int mt = wvi >> 1, nt = wvi & 1;
    f32x4 acc = zero4;
#pragma unroll
    for (int kk = 0; kk < 2; ++kk) {
      f16x8 aY = *(const f16x8*)&xch[(mt * 16 + c16) * XC4 + 64 + kk * 32 + g * 8];
      f16x8 bW;
#pragma unroll
      for (int j = 0; j < 8; ++j)
        bW[j] = (_Float16)Wout[(kk * 32 + g * 8 + j) * 32 + nt * 16 + c16];
      acc = __builtin_amdgcn_mfma_f32_16x16x32_f16(aY, bW, acc, 0, 0, 0);
    }
#pragma unroll
    for (int r = 0; r < 4; ++r) {
      int l = mt * 16 + 4 * g + r;
      int dm = nt * 16 + c16;
      size_t gi = ubase + (size_t)(l0 + l) * DM + dm;
      ym[gi] = __float2half(acc[r] + skipv * __half2float(u[gi]));
    }
  }
}

// ---------------- K5: regroup + LN2 + proj(256x256) via MFMA + transpose ----------------
__global__ __launch_bounds__(256, 4) void k5_ln_proj(const __half* __restrict__ ym,
                                                     const float* __restrict__ lnw,
                                                     const float* __restrict__ lnb,
                                                     const float* __restrict__ pw,
                                                     const float* __restrict__ pb,
                                                     float* __restrict__ outp) {
  __shared__ __align__(16) char buf[33792];  // phase A: yh fp16 [32][YH5] (16896 B)
                                             // phase B: res f32 [256][33] (33792 B)
  __shared__ float mu[32], rs[32], wv[256], bv[256];
  __shared__ float ps[32 * 9], ps2[32 * 9];
  _Float16* yh = (_Float16*)buf;
  float* res = (float*)buf;
  const int b = blockIdx.y, l0 = blockIdx.x * 32, t = threadIdx.x;
  const int lane = t & 63, wvi = t >> 6, g = lane >> 4, c16 = lane & 15;
  const f32x4 zero4 = {0.f, 0.f, 0.f, 0.f};
  wv[t] = lnw[t];
  bv[t] = lnb[t];
  // ---- load ym -> yh fp16 [ll][sp*32+dm] (uint4 moves, 64B runs) ----
#pragma unroll
  for (int i = 0; i < 4; ++i) {
    int idx = i * 256 + t;
    int sp = idx >> 7, rem = idx & 127, ll = rem >> 2, part = rem & 3;
    uint4 v = *(const uint4*)&ym[(((size_t)(sp * B0N + b)) * LSEQ + l0 + ll) * DM + part * 8];
    *(uint4*)&yh[ll * YH5 + sp * 32 + part * 8] = v;
  }
  __syncthreads();
  // ---- LN stats (two-stage parallel) ----
  {
    const int ll = t & 31, seg = t >> 5;
    float s = 0.f, s2 = 0.f;
#pragma unroll 8
    for (int i = 0; i < 32; ++i) {
      float v = (float)yh[ll * YH5 + seg * 32 + i];
      s += v; s2 += v * v;
    }
    ps[ll * 9 + seg] = s;
    ps2[ll * 9 + seg] = s2;
  }
  __syncthreads();
  if (t < 32) {
    float s = 0.f, s2 = 0.f;
#pragma unroll
    for (int seg = 0; seg < 8; ++seg) { s += ps[t * 9 + seg]; s2 += ps2[t * 9 + seg]; }
    float m = s * (1.f / 256.f);
    mu[t] = m;
    rs[t] = rsqrtf(s2 * (1.f / 256.f) - m * m + 1e-5f);
  }
  __syncthreads();
  // ---- LN apply in place (fp16) ----
#pragma unroll
  for (int i = 0; i < 32; ++i) {
    int idx = i * 256 + t;
    int ll = idx >> 8, ch = idx & 255;
    float v = ((float)yh[ll * YH5 + ch] - mu[ll]) * rs[ll] * wv[ch] + bv[ch];
    yh[ll * YH5 + ch] = (_Float16)v;
  }
  __syncthreads();
  // ---- hoist A-frags to registers (16 x f16x8), then overlay res ----
  f16x8 am[16];
#pragma unroll
  for (int mt = 0; mt < 2; ++mt)
#pragma unroll
    for (int kk = 0; kk < 8; ++kk)
      am[mt * 8 + kk] = *(const f16x8*)&yh[(mt * 16 + c16) * YH5 + kk * 32 + g * 8];
  __syncthreads();  // all yh reads complete; buf becomes res
  // ---- proj GEMM: wave wvi owns n-tiles wvi, wvi+4, wvi+8, wvi+12 ----
#pragma unroll
  for (int ni = 0; ni < 4; ++ni) {
    const int col = (wvi + ni * 4) * 16 + c16;
    f32x4 acc0 = zero4, acc1 = zero4;
#pragma unroll
    for (int kk = 0; kk < 8; ++kk) {
      f16x8 bW;
#pragma unroll
      for (int j = 0; j < 8; ++j)
        bW[j] = (_Float16)pw[(size_t)(kk * 32 + g * 8 + j) * 256 + col];
      acc0 = __builtin_amdgcn_mfma_f32_16x16x32_f16(am[kk], bW, acc0, 0, 0, 0);
      acc1 = __builtin_amdgcn_mfma_f32_16x16x32_f16(am[8 + kk], bW, acc1, 0, 0, 0);
    }
    const float bias = pb[col];
#pragma unroll
    for (int r = 0; r < 4; ++r) {
      res[col * 33 + 4 * g + r] = acc0[r] + bias;
      res[col * 33 + 16 + 4 * g + r] = acc1[r] + bias;
    }
  }
  __syncthreads();
  // ---- store (transpose to NCHW) ----
  for (int idx = t; idx < 8192; idx += 256) {
    int o = idx >> 5, l = idx & 31;
    outp[((size_t)(b * 256 + o)) * LSEQ + l0 + l] = res[o * 33 + l];
  }
}

extern "C" void kernel_launch(void* const* d_in, const int* in_sizes, int n_in,
                              void* d_out, int out_size, void* d_ws, size_t ws_size,
                              hipStream_t stream) {
  (void)in_sizes; (void)n_in; (void)out_size;
  const float* x     = (const float*)d_in[0];
  const float* lnw   = (const float*)d_in[1];
  const float* lnb   = (const float*)d_in[2];
  const float* skip  = (const float*)d_in[3];
  const float* pw    = (const float*)d_in[4];
  const float* pb    = (const float*)d_in[5];
  const float* Win   = (const float*)d_in[6];
  const float* convw = (const float*)d_in[7];
  const float* convb = (const float*)d_in[8];
  const float* dtb   = (const float*)d_in[9];
  const float* Alog  = (const float*)d_in[10];
  const float* Dp    = (const float*)d_in[11];
  const float* rmsw  = (const float*)d_in[12];
  const float* Wout  = (const float*)d_in[13];
  float* outp = (float*)d_out;

  // workspace layout (fp16 tensors): total 227,082,240 B (ws cap proven < 491 MB in R1)
  const size_t NEED = 227082240ull;
  if (ws_size < NEED) return;
  char* ws = (char*)d_ws;
  __half* u    = (__half*)ws;                    //  37,748,736 B
  __half* S    = (__half*)(ws + 37748736);       // 150,994,944 B
  float*  cdec = (float*)(ws + 188743680);       //     589,824 B
  __half* ym   = (__half*)(ws + 189333504);      //  37,748,736 B

  k1_ln_split<<<dim3(288, 8), 256, 0, stream>>>(x, lnw, lnb, u);
  k2_states<<<dim3(288, 64), 256, 0, stream>>>(u, Win, convw, convb, dtb, Alog, S, cdec);
  k3_scan<<<dim3(512), 256, 0, stream>>>(S, cdec);
  k4_out<<<dim3(288, 64), 256, 0, stream>>>(u, Win, convw, convb, dtb, Alog, Dp, rmsw,
                                            Wout, skip, S, ym);
  k5_ln_proj<<<dim3(288, 8), 256, 0, stream>>>(ym, lnw, lnb, pw, pb, outp);
}

// Round 9
// 587.734 us; speedup vs baseline: 1.0861x; 1.0736x over previous
//
#include <hip/hip_runtime.h>
#include <hip/hip_fp16.h>
#include <math.h>

typedef unsigned short u16;
typedef unsigned int u32;
typedef _Float16 half2_t __attribute__((ext_vector_type(2)));
typedef _Float16 f16x4 __attribute__((ext_vector_type(4)));
typedef _Float16 f16x8 __attribute__((ext_vector_type(8)));
typedef float f32x4 __attribute__((ext_vector_type(4)));

#define B0N 8
#define LSEQ 9216
#define NSEQ 64
#define NCHUNK 288
#define DM 32
#define DPROJ 264
#define CONVCH 192
#define XC4 208   // k4 xc row stride (fp16, 416B rows -> 16B-aligned for ds_read_b128)
#define URH 40    // ur row stride (fp16, 80B rows -> 16B-aligned, 2-way banks)
#define CTS 40    // transposed conv-intermediate row stride (fp16, 80B rows)
#define ZBS 66    // k4 zbuf row stride (fp16)
#define TTS 40    // k2 transposed xs/B/A row stride (fp16, 80B rows)
#define GS 36     // k4 G row stride (f32, 144B rows -> 16B-aligned)
#define YH5 264   // k5 yh row stride (fp16, 528B rows -> 16B-aligned)

#ifndef __has_builtin
#define __has_builtin(x) 0
#endif

// fast silu: v * rcp(1+exp(-v)); rcp is ~1ulp f32 — far below fp16 output rounding
__device__ __forceinline__ float silu_(float v) {
  return v * __builtin_amdgcn_rcpf(1.f + __expf(-v));
}

// ---------------- K1: LayerNorm(256) + split -> u (64,9216,32) fp16 ----------------
__global__ __launch_bounds__(256) void k1_ln_split(const float* __restrict__ x,
                                                   const float* __restrict__ lnw,
                                                   const float* __restrict__ lnb,
                                                   __half* __restrict__ u) {
  __shared__ float tile[256 * 33];  // [c][ll]
  __shared__ float mu[32], rs[32], wv[256], bv[256];
  __shared__ float ps[32 * 9], ps2[32 * 9];
  const int b = blockIdx.y, l0 = blockIdx.x * 32, t = threadIdx.x;
  wv[t] = lnw[t];
  bv[t] = lnb[t];
#pragma unroll
  for (int i = 0; i < 8; ++i) {
    int idx = i * 256 + t;
    int cc = idx >> 3, part = idx & 7;
    float4 v = *(const float4*)&x[((size_t)b * 256 + cc) * LSEQ + l0 + part * 4];
    tile[cc * 33 + part * 4 + 0] = v.x;
    tile[cc * 33 + part * 4 + 1] = v.y;
    tile[cc * 33 + part * 4 + 2] = v.z;
    tile[cc * 33 + part * 4 + 3] = v.w;
  }
  __syncthreads();
  {
    const int ll = t & 31, seg = t >> 5;
    float s = 0.f, s2 = 0.f;
#pragma unroll 8
    for (int i = 0; i < 32; ++i) {
      float v = tile[(seg * 32 + i) * 33 + ll];
      s += v; s2 += v * v;
    }
    ps[ll * 9 + seg] = s;
    ps2[ll * 9 + seg] = s2;
  }
  __syncthreads();
  if (t < 32) {
    float s = 0.f, s2 = 0.f;
#pragma unroll
    for (int seg = 0; seg < 8; ++seg) { s += ps[t * 9 + seg]; s2 += ps2[t * 9 + seg]; }
    float m = s * (1.f / 256.f);
    mu[t] = m;
    rs[t] = rsqrtf(s2 * (1.f / 256.f) - m * m + 1e-5f);
  }
  __syncthreads();
#pragma unroll 4
  for (int i = 0; i < 32; ++i) {
    int sp = i >> 2, sub = i & 3;
    int ll = sub * 8 + (t >> 5), dm = t & 31;
    int c = sp * 32 + dm;
    float v = (tile[c * 33 + ll] - mu[ll]) * rs[ll] * wv[c] + bv[c];
    u[(((size_t)(sp * B0N + b)) * LSEQ + l0 + ll) * DM + dm] = __float2half(v);
  }
}

// ---------------- K2: in-proj + conv + dt + per-chunk states (MFMA, transposed CH) ----------------
// LDS arena (32512 B):
//   ur_h  [48][URH] fp16 @ 0      (3840 B)
//   CH2T  [128][CTS] fp16 @ 3840  (10240 B)  [ch][row], dead after conv
//   Ah    [64][TTS] fp16 @ 3840   (5120 B)   overlay
//   Sout  [64][72]  fp16 @ 8960   (9216 B)   overlay (CH2T tail + gap; disjoint from Ah)
//   xst   [64][TTS] fp16 @ 18176  (5120 B)
//   Bt    [64][TTS] fp16 @ 23296  (5120 B)
//   dtraw/dtv/acs/wv2 f32[256] @ 28416..32512
__global__ __launch_bounds__(256, 4) void k2_states(
    const __half* __restrict__ u, const float* __restrict__ Win,
    const float* __restrict__ convw, const float* __restrict__ convb,
    const float* __restrict__ dtbias, const float* __restrict__ Alog,
    __half* __restrict__ S, float* __restrict__ cdec) {
  __shared__ __align__(16) char smem[32512];
  _Float16* ur_h = (_Float16*)smem;
  _Float16* CH2T = (_Float16*)(smem + 3840);
  _Float16* Ah   = (_Float16*)(smem + 3840);
  __half*   Sout = (__half*)(smem + 8960);
  _Float16* xst  = (_Float16*)(smem + 18176);
  _Float16* Bt   = (_Float16*)(smem + 23296);
  float* dtraw = (float*)(smem + 28416);
  float* dtv   = (float*)(smem + 29440);
  float* acs   = (float*)(smem + 30464);
  float* wv2   = (float*)(smem + 31488);
  const int c = blockIdx.x, sq = blockIdx.y, t = threadIdx.x;
  const int l0 = c * 32;
  const int lane = t & 63, wvi = t >> 6, g = lane >> 4, c16 = lane & 15;
  const size_t ubase = (size_t)sq * (LSEQ * DM);
  const f32x4 zero4 = {0.f, 0.f, 0.f, 0.f};

  // ---- P0: stage ur (fp16); load Win B-frags (cols 64..191 -> channels 0..127) ----
  for (int idx = t; idx < 48 * 32; idx += 256) {
    int r = idx >> 5, dm = idx & 31;
    int l = l0 - 2 + r;
    _Float16 v = (_Float16)0.f;
    if (r < 34 && l >= 0) v = ((const _Float16*)u)[ubase + (size_t)l * DM + dm];
    ur_h[r * URH + dm] = v;
  }
  f16x8 bfr[2];  // N-tiles nt = wvi, wvi+4
#pragma unroll
  for (int i = 0; i < 2; ++i) {
    int col = 64 + (wvi + i * 4) * 16 + c16;
#pragma unroll
    for (int j = 0; j < 8; ++j) bfr[i][j] = (_Float16)Win[(g * 8 + j) * DPROJ + col];
  }
  __syncthreads();

  // ---- P1: MFMA inproj -> CH2T[ch][row] (fp16, vector stores) ----
  {
    f16x8 am[3];
#pragma unroll
    for (int mt = 0; mt < 3; ++mt)
      am[mt] = *(const f16x8*)&ur_h[(mt * 16 + c16) * URH + g * 8];
#pragma unroll
    for (int i = 0; i < 2; ++i) {
      int colc = (wvi + i * 4) * 16 + c16;
#pragma unroll
      for (int mt = 0; mt < 3; ++mt) {
        f32x4 acc = __builtin_amdgcn_mfma_f32_16x16x32_f16(am[mt], bfr[i], zero4, 0, 0, 0);
        if (mt < 2) {
          f16x4 o;
          o[0] = (_Float16)acc[0]; o[1] = (_Float16)acc[1];
          o[2] = (_Float16)acc[2]; o[3] = (_Float16)acc[3];
          *(f16x4*)&CH2T[colc * CTS + mt * 16 + 4 * g] = o;
        } else if (g == 0) {  // rows 32,33 only
          half2_t o;
          o.x = (_Float16)acc[0]; o.y = (_Float16)acc[1];
          *(half2_t*)&CH2T[colc * CTS + 32] = o;
        }
      }
    }
  }
  __syncthreads();

  // ---- P2: conv+silu -> xst/Bt (vector CH2T reads, rolling 3-tap); dtraw f32 dot ----
  {
    const int ch0 = t & 63, lbq = t >> 6;  // rows lbq*8 .. lbq*8+7
#pragma unroll
    for (int cr = 0; cr < 2; ++cr) {
      int ch = ch0 + cr * 64;
      float w0 = convw[ch * 3 + 0], w1 = convw[ch * 3 + 1], w2 = convw[ch * 3 + 2];
      float cb = convb[ch];
      f16x8 v8 = *(const f16x8*)&CH2T[ch * CTS + lbq * 8];
      half2_t v2 = *(const half2_t*)&CH2T[ch * CTS + lbq * 8 + 8];
      float v[10];
#pragma unroll
      for (int j = 0; j < 8; ++j) v[j] = (float)v8[j];
      v[8] = (float)v2.x; v[9] = (float)v2.y;
      f16x8 out;
#pragma unroll
      for (int j = 0; j < 8; ++j)
        out[j] = (_Float16)silu_(v[j] * w0 + v[j + 1] * w1 + v[j + 2] * w2 + cb);
      if (cr == 0) *(f16x8*)&xst[ch0 * TTS + lbq * 8] = out;
      else         *(f16x8*)&Bt[ch0 * TTS + lbq * 8] = out;
    }
    int l = t >> 3, h = t & 7;
    float raw = 0.f;
#pragma unroll
    for (int dm = 0; dm < 32; ++dm)
      raw += (float)ur_h[(l + 2) * URH + dm] * Win[dm * DPROJ + 256 + h];
    dtraw[l * 8 + h] = raw;
  }
  __syncthreads();

  // ---- P3: dt softplus + prefix scan (parallel; 32-lane Kogge-Stone) + cdec ----
  {
    const int l = t & 31, h = t >> 5;
    float raw = dtraw[l * 8 + h] + dtbias[h];
    float dt = (raw > 20.f) ? raw : log1pf(__expf(raw));
    float x = dt;
#pragma unroll
    for (int d = 1; d < 32; d <<= 1) {
      float y = __shfl_up(x, d, 32);
      if (l >= d) x += y;
    }
    const float A = -__expf(Alog[h]);
    dtv[t] = dt;
    acs[t] = A * x;
    if (l == 31) cdec[(sq * NCHUNK + c) * 8 + h] = __expf(A * x);
  }
  __syncthreads();

  // ---- P4: wv2; build A[hp][l] = wv2[h][l]*xs[l][hp] (fp16, overlay) ----
  {
    int h = t >> 5;
    wv2[t] = __expf(acs[h * 32 + 31] - acs[t]) * dtv[t];
  }
  __syncthreads();
  {
    const int hp = t >> 2, lb2 = (t & 3) * 8;
    const float* w = &wv2[(hp >> 3) * 32 + lb2];
    const _Float16* xr = &xst[hp * TTS + lb2];
    f16x8 ov;
#pragma unroll
    for (int i = 0; i < 8; ++i) ov[i] = (_Float16)((float)xr[i] * w[i]);
    *(f16x8*)&Ah[hp * TTS + lb2] = ov;
  }
  __syncthreads();

  // ---- P5: states MFMA S[hp][n] = A·B -> Sout, then coalesced global store ----
  {
    const int mt = wvi;
    f16x8 aS = *(const f16x8*)&Ah[(mt * 16 + c16) * TTS + g * 8];
#pragma unroll
    for (int nt = 0; nt < 4; ++nt) {
      f16x8 bS = *(const f16x8*)&Bt[(nt * 16 + c16) * TTS + g * 8];
      f32x4 acc = __builtin_amdgcn_mfma_f32_16x16x32_f16(aS, bS, zero4, 0, 0, 0);
#pragma unroll
      for (int r = 0; r < 4; ++r)
        Sout[(mt * 16 + 4 * g + r) * 72 + nt * 16 + c16] = __float2half(acc[r]);
    }
  }
  __syncthreads();
  const size_t sbase = (size_t)(sq * NCHUNK + c) * 4096;
#pragma unroll
  for (int i = 0; i < 2; ++i) {
    int idx = i * 256 + t;
    int hp = idx >> 3, part = idx & 7;
    *(uint4*)(S + sbase + hp * 64 + part * 8) = *(const uint4*)&Sout[hp * 72 + part * 8];
  }
}

// ---------------- K3: in-place exclusive scan (256 thr, u32 grain, 8-deep prefetch) ----------------
__global__ __launch_bounds__(256) void k3_scan(__half* __restrict__ S,
                                               const float* __restrict__ cdec) {
  __shared__ float cd[NCHUNK];
  const int sq = blockIdx.x >> 3, h = blockIdx.x & 7, t = threadIdx.x;
  for (int i = t; i < NCHUNK; i += 256) cd[i] = cdec[(sq * NCHUNK + i) * 8 + h];
  __syncthreads();
  __half* p = S + (size_t)sq * NCHUNK * 4096 + h * 512 + t * 2;
  u32 f0 = *(const u32*)(p);
  u32 f1 = *(const u32*)(p + 4096);
  u32 f2 = *(const u32*)(p + 2 * 4096);
  u32 f3 = *(const u32*)(p + 3 * 4096);
  u32 f4 = *(const u32*)(p + 4 * 4096);
  u32 f5 = *(const u32*)(p + 5 * 4096);
  u32 f6 = *(const u32*)(p + 6 * 4096);
  u32 f7 = *(const u32*)(p + 7 * 4096);
  float car0 = 0.f, car1 = 0.f;
  for (int c = 0; c < NCHUNK; c += 8) {
#define K3_STEP(F, K)                                                    \
    {                                                                    \
      half2_t s2h = *(half2_t*)&F;                                       \
      float s0 = (float)s2h.x, s1 = (float)s2h.y;                        \
      int nc = c + K + 8; if (nc > NCHUNK - 1) nc = NCHUNK - 1;          \
      F = *(const u32*)(p + (size_t)nc * 4096);                          \
      half2_t o; o.x = (_Float16)car0; o.y = (_Float16)car1;             \
      *(u32*)(p + (size_t)(c + K) * 4096) = *(u32*)&o;                   \
      float d = cd[c + K];                                               \
      car0 = car0 * d + s0; car1 = car1 * d + s1;                        \
    }
    K3_STEP(f0, 0)
    K3_STEP(f1, 1)
    K3_STEP(f2, 2)
    K3_STEP(f3, 3)
    K3_STEP(f4, 4)
    K3_STEP(f5, 5)
    K3_STEP(f6, 6)
    K3_STEP(f7, 7)
#undef K3_STEP
  }
}

// ---------------- K4: output pass — MFMA; transposed conv-CH; fused Yd/Yo/gate ----------------
// MFMA 16x16x32 f16 conventions (gfx950), verified R2:
//   A frag: lane holds A[row = lane&15][k = (lane>>4)*8 + j], j=0..7
//   B frag: lane holds B[k = (lane>>4)*8 + j][col = lane&15]
//   D frag: lane reg r holds D[row = 4*(lane>>4)+r][col = lane&15]
// LDS (39808 B -> 4 blocks/CU):
//   ur_h [48][URH] 3840 (scl f32[32] overlay after P2)
//   CHhT [192][CTS] 15360; overlay after conv: pv fp16[64][72] @0 (9216),
//                                              G f32[32][36] @9216 (4608) -> RMS partials
//   xch  [32][XC4] 13312; dtraw/dtv/acs 3072; zbuf 4224
__global__ __launch_bounds__(256, 4) void k4_out(
    const __half* __restrict__ u, const float* __restrict__ Win,
    const float* __restrict__ convw, const float* __restrict__ convb,
    const float* __restrict__ dtbias, const float* __restrict__ Alog,
    const float* __restrict__ Dp, const float* __restrict__ rmsw,
    const float* __restrict__ Wout, const float* __restrict__ skip,
    const __half* __restrict__ S, __half* __restrict__ ym) {
  __shared__ __align__(16) _Float16 ur_h[48 * URH];
  __shared__ __align__(16) _Float16 CHhT[192 * CTS];
  __shared__ __align__(16) __half xch[32 * XC4];
  __shared__ __align__(16) float dtraw[256];  // dtraw [l][h]; later eac[h*32+l]
  __shared__ __align__(16) float dtv[256], acs[256];
  __shared__ __align__(16) _Float16 zbuf[32 * ZBS];
  const int c = blockIdx.x, sq = blockIdx.y, t = threadIdx.x;
  const int l0 = c * 32;
  const int lane = t & 63, wvi = t >> 6, g = lane >> 4, c16 = lane & 15;
  const size_t ubase = (size_t)sq * (LSEQ * DM);
  const f32x4 zero4 = {0.f, 0.f, 0.f, 0.f};

  // ---- P0: stage ur (fp16), load B-frags (Win via L2), prefetch S into regs ----
  const size_t sbase = (size_t)(sq * NCHUNK + c) * 4096;
  uint4 sv0, sv1;
  {
    const uint4* sp = (const uint4*)(S + sbase);
    sv0 = sp[t * 2];
    sv1 = sp[t * 2 + 1];
  }
  for (int idx = t; idx < 48 * 32; idx += 256) {
    int r = idx >> 5, dm = idx & 31;
    int l = l0 - 2 + r;
    _Float16 v = (_Float16)0.f;
    if (r < 34 && l >= 0) v = ((const _Float16*)u)[ubase + (size_t)l * DM + dm];
    ur_h[r * URH + dm] = v;
  }
  f16x8 bfr[3];  // inproj N-tiles nt = wvi, wvi+4, wvi+8
#pragma unroll
  for (int i = 0; i < 3; ++i) {
    int col = 64 + (wvi + i * 4) * 16 + c16;
#pragma unroll
    for (int j = 0; j < 8; ++j) bfr[i][j] = (_Float16)Win[(g * 8 + j) * DPROJ + col];
  }
  f16x8 bz;  // z N-tile: cols wvi*16..
  {
    int col = wvi * 16 + c16;
#pragma unroll
    for (int j = 0; j < 8; ++j) bz[j] = (_Float16)Win[(g * 8 + j) * DPROJ + col];
  }
  __syncthreads();

  // ---- P1: MFMA inproj -> CHhT[ch][row] (vector stores), z -> zbuf ----
  {
    f16x8 am[3];
#pragma unroll
    for (int mt = 0; mt < 3; ++mt)
      am[mt] = *(const f16x8*)&ur_h[(mt * 16 + c16) * URH + g * 8];
#pragma unroll
    for (int i = 0; i < 3; ++i) {
      int colc = (wvi + i * 4) * 16 + c16;
#pragma unroll
      for (int mt = 0; mt < 3; ++mt) {
        f32x4 acc = __builtin_amdgcn_mfma_f32_16x16x32_f16(am[mt], bfr[i], zero4, 0, 0, 0);
        if (mt < 2) {
          f16x4 o;
          o[0] = (_Float16)acc[0]; o[1] = (_Float16)acc[1];
          o[2] = (_Float16)acc[2]; o[3] = (_Float16)acc[3];
          *(f16x4*)&CHhT[colc * CTS + mt * 16 + 4 * g] = o;
        } else if (g == 0) {  // rows 32,33
          half2_t o;
          o.x = (_Float16)acc[0]; o.y = (_Float16)acc[1];
          *(half2_t*)&CHhT[colc * CTS + 32] = o;
        }
      }
    }
#pragma unroll
    for (int mz = 0; mz < 2; ++mz) {
      f16x8 az = *(const f16x8*)&ur_h[(2 + mz * 16 + c16) * URH + g * 8];
      f32x4 acc = __builtin_amdgcn_mfma_f32_16x16x32_f16(az, bz, zero4, 0, 0, 0);
#pragma unroll
      for (int r = 0; r < 4; ++r) {
        int lY = mz * 16 + 4 * g + r;
        zbuf[lY * ZBS + wvi * 16 + c16] = (_Float16)acc[r];
      }
    }
  }
  __syncthreads();

  // ---- P2: conv+silu -> xch (vector CHhT reads); dtraw via f32 scalar dot ----
  {
    const int ch0 = t & 63, lbq = t >> 6;  // rows lbq*8 .. lbq*8+7
#pragma unroll
    for (int cr = 0; cr < 3; ++cr) {
      int ch = ch0 + cr * 64;
      float w0 = convw[ch * 3 + 0], w1 = convw[ch * 3 + 1], w2 = convw[ch * 3 + 2];
      float cb = convb[ch];
      f16x8 v8 = *(const f16x8*)&CHhT[ch * CTS + lbq * 8];
      half2_t v2 = *(const half2_t*)&CHhT[ch * CTS + lbq * 8 + 8];
      float v[10];
#pragma unroll
      for (int j = 0; j < 8; ++j) v[j] = (float)v8[j];
      v[8] = (float)v2.x; v[9] = (float)v2.y;
#pragma unroll
      for (int j = 0; j < 8; ++j) {
        float s = v[j] * w0 + v[j + 1] * w1 + v[j + 2] * w2 + cb;
        xch[(lbq * 8 + j) * XC4 + ch] = __float2half(silu_(s));
      }
    }
    int l = t >> 3, h = t & 7;
    float raw = 0.f;
#pragma unroll
    for (int dm = 0; dm < 32; ++dm)
      raw += (float)ur_h[(l + 2) * URH + dm] * Win[dm * DPROJ + 256 + h];
    dtraw[l * 8 + h] = raw;
  }
  __syncthreads();

  // ---- P3: pv <- S regs (CHhT overlay); dt softplus + parallel prefix scan ----
  {
    char* pvb = (char*)CHhT;
    int hp = t >> 2, part = t & 3;
    *(uint4*)(pvb + hp * 144 + part * 32) = sv0;
    *(uint4*)(pvb + hp * 144 + part * 32 + 16) = sv1;
  }
  {
    const int l = t & 31, h = t >> 5;
    float raw = dtraw[l * 8 + h] + dtbias[h];
    float dt = (raw > 20.f) ? raw : log1pf(__expf(raw));
    float x = dt;
#pragma unroll
    for (int d = 1; d < 32; d <<= 1) {
      float y = __shfl_up(x, d, 32);
      if (l >= d) x += y;
    }
    dtv[t] = dt;
    acs[t] = -__expf(Alog[h]) * x;
  }
  __syncthreads();

  // ---- P4: eac table; G = C·B^T via MFMA (stride GS=36) ----
  float* Gm = (float*)((char*)CHhT + 9216);
  {
    float ev = __expf(acs[t]);
    dtraw[t] = ev;  // eac[h*32+l]
    const int mt = wvi >> 1, nt = wvi & 1;
    f32x4 acc = zero4;
#pragma unroll
    for (int kk = 0; kk < 2; ++kk) {
      f16x8 aC = *(const f16x8*)&xch[(mt * 16 + c16) * XC4 + 128 + kk * 32 + g * 8];
      f16x8 bB = *(const f16x8*)&xch[(nt * 16 + c16) * XC4 + 64 + kk * 32 + g * 8];
      acc = __builtin_amdgcn_mfma_f32_16x16x32_f16(aC, bB, acc, 0, 0, 0);
    }
#pragma unroll
    for (int r = 0; r < 4; ++r)
      Gm[(mt * 16 + 4 * g + r) * GS + nt * 16 + c16] = acc[r];
  }
  __syncthreads();

  // ---- P5: Yd via MFMA — masked M-fragments in registers; dacc stays in regs ----
  // M_h[row][s2] = (s2<=row) ? G[row][s2]*exp(acs_row - acs_s2)*dtv[s2] : 0
  // D cols 8..15 duplicate cols 0..7 (B col = c16&7)
  float dacc[2][2][4];  // [hh][mt][r]
  {
    const int s2b = g * 8;
    float gv[2][8];
#pragma unroll
    for (int mt = 0; mt < 2; ++mt) {
      const float* gr = &Gm[(mt * 16 + c16) * GS + s2b];
      float4 g0 = *(const float4*)gr;
      float4 g1 = *(const float4*)(gr + 4);
      gv[mt][0] = g0.x; gv[mt][1] = g0.y; gv[mt][2] = g0.z; gv[mt][3] = g0.w;
      gv[mt][4] = g1.x; gv[mt][5] = g1.y; gv[mt][6] = g1.z; gv[mt][7] = g1.w;
    }
#pragma unroll
    for (int hh = 0; hh < 2; ++hh) {
      const int h = 2 * wvi + hh;
      const float* ap = &acs[h * 32 + s2b];
      const float* dp = &dtv[h * 32 + s2b];
      float4 a0 = *(const float4*)ap, a1 = *(const float4*)(ap + 4);
      float4 d0 = *(const float4*)dp, d1 = *(const float4*)(dp + 4);
      const float av[8] = {a0.x, a0.y, a0.z, a0.w, a1.x, a1.y, a1.z, a1.w};
      const float dv[8] = {d0.x, d0.y, d0.z, d0.w, d1.x, d1.y, d1.z, d1.w};
      f16x8 bfr2;
#pragma unroll
      for (int j = 0; j < 8; ++j)
        bfr2[j] = *(const _Float16*)&xch[(s2b + j) * XC4 + h * 8 + (c16 & 7)];
#pragma unroll
      for (int mt = 0; mt < 2; ++mt) {
        const int row = mt * 16 + c16;
        const float arow = acs[h * 32 + row];
        f16x8 afr;
#pragma unroll
        for (int j = 0; j < 8; ++j) {
          float m = gv[mt][j] * __expf(arow - av[j]) * dv[j];
          afr[j] = (_Float16)((s2b + j <= row) ? m : 0.f);
        }
        f32x4 d = __builtin_amdgcn_mfma_f32_16x16x32_f16(afr, bfr2, zero4, 0, 0, 0);
#pragma unroll
        for (int r = 0; r < 4; ++r) dacc[hh][mt][r] = d[r];
      }
    }
  }
  // no barrier: Yd handoff is intra-wave (shuffle)

  // ---- P6 (fused): Yo MFMA + Yd shuffle + eac-scale + D*xs + silu(z) gate; one ybuf write ----
  {
    const __half* pvh = (const __half*)CHhT;  // [64][72] fp16
    const int hp = wvi * 16 + c16;
    const float dcoef = Dp[hp >> 3];
    const int srcLane = g * 16 + (c16 & 7);
#pragma unroll
    for (int mt = 0; mt < 2; ++mt) {
      f32x4 acc = zero4;
#pragma unroll
      for (int kk = 0; kk < 2; ++kk) {
        f16x8 aC = *(const f16x8*)&xch[(mt * 16 + c16) * XC4 + 128 + kk * 32 + g * 8];
        f16x8 bP = *(const f16x8*)&pvh[(wvi * 16 + c16) * 72 + kk * 32 + g * 8];
        acc = __builtin_amdgcn_mfma_f32_16x16x32_f16(aC, bP, acc, 0, 0, 0);
      }
#pragma unroll
      for (int r = 0; r < 4; ++r) {
        int l = mt * 16 + 4 * g + r;
        float yd0 = __shfl(dacc[0][mt][r], srcLane, 64);
        float yd1 = __shfl(dacc[1][mt][r], srcLane, 64);
        float yd = (c16 < 8) ? yd0 : yd1;
        float e = dtraw[(hp >> 3) * 32 + l];
        float xs = __half2float(xch[l * XC4 + hp]);
        float y = yd + acc[r] * e + xs * dcoef;
        float z = (float)zbuf[l * ZBS + hp];
        y *= z * __builtin_amdgcn_rcpf(1.f + __expf(-z));
        xch[l * XC4 + 64 + hp] = __float2half(y);
      }
    }
  }
  __syncthreads();

  // ---- P8: RMS scale factors (two-stage parallel reduce) ----
  float* rp = Gm;                  // [32][9] partials (G dead after P5)
  float* scl = (float*)ur_h;       // ur dead after P2
  {
    const int l = t & 31, seg = t >> 5;
    float p = 0.f;
#pragma unroll
    for (int k = 0; k < 8; ++k) {
      float v = __half2float(xch[l * XC4 + 64 + seg * 8 + k]);
      p += v * v;
    }
    rp[l * 9 + seg] = p;
  }
  __syncthreads();
  if (t < 32) {
    float s2s = 0.f;
#pragma unroll
    for (int seg = 0; seg < 8; ++seg) s2s += rp[t * 9 + seg];
    scl[t] = rsqrtf(s2s * (1.f / 64.f) + 1e-5f);
  }
  __syncthreads();

  // ---- P9: apply rms * rmsw ----
  for (int idx = t; idx < 2048; idx += 256) {
    int l = idx >> 6, hp = idx & 63;
    xch[l * XC4 + 64 + hp] =
        __float2half(__half2float(xch[l * XC4 + 64 + hp]) * scl[l] * rmsw[hp]);
  }
  __syncthreads();

  // ---- P10: y @ Wout via MFMA + skip, store ym ----
  {
    const float skipv = skip[0];
    const int mt = wvi >> 1, nt = wvi & 1;
    f32x4 acc = zero4;
#pragma unroll
    for (int kk = 0; kk < 2; ++kk) {
      f16x8 aY = *(const f16x8*)&xch[(mt * 16 + c16) * XC4 + 64 + kk * 32 + g * 8];
      f16x8 bW;
#pragma unroll
      for (int j = 0; j < 8; ++j)
        bW[j] = (_Float16)Wout[(kk * 32 + g * 8 + j) * 32 + nt * 16 + c16];
      acc = __builtin_amdgcn_mfma_f32_16x16x32_f16(aY, bW, acc, 0, 0, 0);
    }
#pragma unroll
    for (int r = 0; r < 4; ++r) {
      int l = mt * 16 + 4 * g + r;
      int dm = nt * 16 + c16;
      size_t gi = ubase + (size_t)(l0 + l) * DM + dm;
      ym[gi] = __float2half(acc[r] + skipv * __half2float(u[gi]));
    }
  }
}

// ---------------- K5: regroup + LN2 + proj(256x256) via MFMA + transpose ----------------
__global__ __launch_bounds__(256, 4) void k5_ln_proj(const __half* __restrict__ ym,
                                                     const float* __restrict__ lnw,
                                                     const float* __restrict__ lnb,
                                                     const float* __restrict__ pw,
                                                     const float* __restrict__ pb,
                                                     float* __restrict__ outp) {
  __shared__ __align__(16) char buf[33792];  // phase A: yh fp16 [32][YH5] (16896 B)
                                             // phase B: res f32 [256][33] (33792 B)
  __shared__ float mu[32], rs[32], wv[256], bv[256];
  __shared__ float ps[32 * 9], ps2[32 * 9];
  _Float16* yh = (_Float16*)buf;
  float* res = (float*)buf;
  const int b = blockIdx.y, l0 = blockIdx.x * 32, t = threadIdx.x;
  const int lane = t & 63, wvi = t >> 6, g = lane >> 4, c16 = lane & 15;
  const f32x4 zero4 = {0.f, 0.f, 0.f, 0.f};
  wv[t] = lnw[t];
  bv[t] = lnb[t];
  // ---- load ym -> yh fp16 [ll][sp*32+dm] (uint4 moves, 64B runs) ----
#pragma unroll
  for (int i = 0; i < 4; ++i) {
    int idx = i * 256 + t;
    int sp = idx >> 7, rem = idx & 127, ll = rem >> 2, part = rem & 3;
    uint4 v = *(const uint4*)&ym[(((size_t)(sp * B0N + b)) * LSEQ + l0 + ll) * DM + part * 8];
    *(uint4*)&yh[ll * YH5 + sp * 32 + part * 8] = v;
  }
  __syncthreads();
  // ---- LN stats (two-stage parallel) ----
  {
    const int ll = t & 31, seg = t >> 5;
    float s = 0.f, s2 = 0.f;
#pragma unroll 8
    for (int i = 0; i < 32; ++i) {
      float v = (float)yh[ll * YH5 + seg * 32 + i];
      s += v; s2 += v * v;
    }
    ps[ll * 9 + seg] = s;
    ps2[ll * 9 + seg] = s2;
  }
  __syncthreads();
  if (t < 32) {
    float s = 0.f, s2 = 0.f;
#pragma unroll
    for (int seg = 0; seg < 8; ++seg) { s += ps[t * 9 + seg]; s2 += ps2[t * 9 + seg]; }
    float m = s * (1.f / 256.f);
    mu[t] = m;
    rs[t] = rsqrtf(s2 * (1.f / 256.f) - m * m + 1e-5f);
  }
  __syncthreads();
  // ---- LN apply in place (fp16) ----
#pragma unroll
  for (int i = 0; i < 32; ++i) {
    int idx = i * 256 + t;
    int ll = idx >> 8, ch = idx & 255;
    float v = ((float)yh[ll * YH5 + ch] - mu[ll]) * rs[ll] * wv[ch] + bv[ch];
    yh[ll * YH5 + ch] = (_Float16)v;
  }
  __syncthreads();
  // ---- hoist A-frags to registers (16 x f16x8), then overlay res ----
  f16x8 am[16];
#pragma unroll
  for (int mt = 0; mt < 2; ++mt)
#pragma unroll
    for (int kk = 0; kk < 8; ++kk)
      am[mt * 8 + kk] = *(const f16x8*)&yh[(mt * 16 + c16) * YH5 + kk * 32 + g * 8];
  __syncthreads();  // all yh reads complete; buf becomes res
  // ---- proj GEMM: wave wvi owns n-tiles wvi, wvi+4, wvi+8, wvi+12 ----
#pragma unroll
  for (int ni = 0; ni < 4; ++ni) {
    const int col = (wvi + ni * 4) * 16 + c16;
    f32x4 acc0 = zero4, acc1 = zero4;
#pragma unroll
    for (int kk = 0; kk < 8; ++kk) {
      f16x8 bW;
#pragma unroll
      for (int j = 0; j < 8; ++j)
        bW[j] = (_Float16)pw[(size_t)(kk * 32 + g * 8 + j) * 256 + col];
      acc0 = __builtin_amdgcn_mfma_f32_16x16x32_f16(am[kk], bW, acc0, 0, 0, 0);
      acc1 = __builtin_amdgcn_mfma_f32_16x16x32_f16(am[8 + kk], bW, acc1, 0, 0, 0);
    }
    const float bias = pb[col];
#pragma unroll
    for (int r = 0; r < 4; ++r) {
      res[col * 33 + 4 * g + r] = acc0[r] + bias;
      res[col * 33 + 16 + 4 * g + r] = acc1[r] + bias;
    }
  }
  __syncthreads();
  // ---- store (transpose to NCHW) ----
  for (int idx = t; idx < 8192; idx += 256) {
    int o = idx >> 5, l = idx & 31;
    outp[((size_t)(b * 256 + o)) * LSEQ + l0 + l] = res[o * 33 + l];
  }
}

extern "C" void kernel_launch(void* const* d_in, const int* in_sizes, int n_in,
                              void* d_out, int out_size, void* d_ws, size_t ws_size,
                              hipStream_t stream) {
  (void)in_sizes; (void)n_in; (void)out_size;
  const float* x     = (const float*)d_in[0];
  const float* lnw   = (const float*)d_in[1];
  const float* lnb   = (const float*)d_in[2];
  const float* skip  = (const float*)d_in[3];
  const float* pw    = (const float*)d_in[4];
  const float* pb    = (const float*)d_in[5];
  const float* Win   = (const float*)d_in[6];
  const float* convw = (const float*)d_in[7];
  const float* convb = (const float*)d_in[8];
  const float* dtb   = (const float*)d_in[9];
  const float* Alog  = (const float*)d_in[10];
  const float* Dp    = (const float*)d_in[11];
  const float* rmsw  = (const float*)d_in[12];
  const float* Wout  = (const float*)d_in[13];
  float* outp = (float*)d_out;

  // workspace layout (fp16 tensors): total 227,082,240 B (ws cap proven < 491 MB in R1)
  const size_t NEED = 227082240ull;
  if (ws_size < NEED) return;
  char* ws = (char*)d_ws;
  __half* u    = (__half*)ws;                    //  37,748,736 B
  __half* S    = (__half*)(ws + 37748736);       // 150,994,944 B
  float*  cdec = (float*)(ws + 188743680);       //     589,824 B
  __half* ym   = (__half*)(ws + 189333504);      //  37,748,736 B

  k1_ln_split<<<dim3(288, 8), 256, 0, stream>>>(x, lnw, lnb, u);
  k2_states<<<dim3(288, 64), 256, 0, stream>>>(u, Win, convw, convb, dtb, Alog, S, cdec);
  k3_scan<<<dim3(512), 256, 0, stream>>>(S, cdec);
  k4_out<<<dim3(288, 64), 256, 0, stream>>>(u, Win, convw, convb, dtb, Alog, Dp, rmsw,
                                            Wout, skip, S, ym);
  k5_ln_proj<<<dim3(288, 8), 256, 0, stream>>>(ym, lnw, lnb, pw, pb, outp);
}